// Round 1
// baseline (2233.926 us; speedup 1.0000x reference)
//
#include <hip/hip_runtime.h>
#include <hip/hip_bf16.h>

typedef __bf16 bf16_t;
typedef __bf16 bf16x8 __attribute__((ext_vector_type(8)));
typedef float floatx4 __attribute__((ext_vector_type(4)));

#define S_LEN 2048
#define D_DIM 2048
#define NHEADS 32
#define DH 64

// ---------------- f32 -> bf16 elementwise convert ----------------
__global__ __launch_bounds__(256) void k_cvt_bf16(const float* __restrict__ x,
                                                  bf16_t* __restrict__ y, int n) {
    int i = (blockIdx.x * 256 + threadIdx.x) * 8;
    if (i + 8 > n) return;
    const float4 a = *(const float4*)(x + i);
    const float4 b = *(const float4*)(x + i + 4);
    bf16x8 o;
    o[0] = (bf16_t)a.x; o[1] = (bf16_t)a.y; o[2] = (bf16_t)a.z; o[3] = (bf16_t)a.w;
    o[4] = (bf16_t)b.x; o[5] = (bf16_t)b.y; o[6] = (bf16_t)b.z; o[7] = (bf16_t)b.w;
    *(bf16x8*)(y + i) = o;
}

// ---------------- W[k][n] f32 -> Wt[n][k] bf16 ----------------
__global__ __launch_bounds__(256) void k_transpose_bf16(const float* __restrict__ W,
                                                        bf16_t* __restrict__ Wt) {
    __shared__ float tile[64][65];
    const int n0 = blockIdx.x * 64, k0 = blockIdx.y * 64;
    const int tx = threadIdx.x & 63, ty = threadIdx.x >> 6;
    #pragma unroll
    for (int i = 0; i < 16; ++i) {
        int r = i * 4 + ty;
        tile[r][tx] = W[(size_t)(k0 + r) * D_DIM + n0 + tx];
    }
    __syncthreads();
    #pragma unroll
    for (int i = 0; i < 16; ++i) {
        int r = i * 4 + ty;  // n index within tile
        Wt[(size_t)(n0 + r) * D_DIM + k0 + tx] = (bf16_t)tile[tx][r];
    }
}

// ---------------- GEMM: C[m][n] = sum_k A[m][k]*Bt[n][k] + bias[n] ----------------
// A: MxK bf16 row-major, Bt: NxK bf16 row-major (pre-transposed W), C f32.
// 128x128 tile, 4 waves each computing 64x64 via 4x4 mfma_f32_16x16x32_bf16.
#define BM 128
#define BN 128
#define BK 32
#define LDK 40  // BK + 8 pad (80B rows: 16B-aligned, 2-way bank aliasing = free)

__global__ __launch_bounds__(256) void k_gemm_bt(
    const bf16_t* __restrict__ A,
    const bf16_t* __restrict__ Bt0, const bf16_t* __restrict__ Bt1, const bf16_t* __restrict__ Bt2,
    const float* __restrict__ bias0, const float* __restrict__ bias1, const float* __restrict__ bias2,
    float* __restrict__ C0, float* __restrict__ C1, float* __restrict__ C2,
    int M, int N, int K)
{
    const bf16_t* Bt; const float* bias; float* C;
    if (blockIdx.z == 0)      { Bt = Bt0; bias = bias0; C = C0; }
    else if (blockIdx.z == 1) { Bt = Bt1; bias = bias1; C = C1; }
    else                      { Bt = Bt2; bias = bias2; C = C2; }

    __shared__ bf16_t As[BM][LDK];
    __shared__ bf16_t Bs[BN][LDK];

    const int t    = threadIdx.x;
    const int lane = t & 63;
    const int wave = t >> 6;
    const int wm = (wave >> 1) * 64;
    const int wn = (wave & 1) * 64;
    const int bm = blockIdx.y * BM;
    const int bn = blockIdx.x * BN;
    const int lm = lane & 15;   // A row / B col within 16
    const int lq = lane >> 4;   // quad: k = lq*8 + j

    // staging: thread t loads 16 bf16 of row sr, cols sc..sc+15
    const int sr = t >> 1;
    const int sc = (t & 1) * 16;

    floatx4 acc[4][4];
    #pragma unroll
    for (int i = 0; i < 4; ++i)
        #pragma unroll
        for (int j = 0; j < 4; ++j)
            #pragma unroll
            for (int r = 0; r < 4; ++r) acc[i][j][r] = 0.f;

    const bf16_t* Aptr = A  + (size_t)(bm + sr) * K + sc;
    const bf16_t* Bptr = Bt + (size_t)(bn + sr) * K + sc;

    for (int k0 = 0; k0 < K; k0 += BK) {
        const uint4 av0 = *(const uint4*)(Aptr + k0);
        const uint4 av1 = *(const uint4*)(Aptr + k0 + 8);
        const uint4 bv0 = *(const uint4*)(Bptr + k0);
        const uint4 bv1 = *(const uint4*)(Bptr + k0 + 8);
        __syncthreads();  // previous iter's fragment reads done
        *(uint4*)&As[sr][sc]     = av0;
        *(uint4*)&As[sr][sc + 8] = av1;
        *(uint4*)&Bs[sr][sc]     = bv0;
        *(uint4*)&Bs[sr][sc + 8] = bv1;
        __syncthreads();

        bf16x8 af[4], bfr[4];
        #pragma unroll
        for (int i = 0; i < 4; ++i)
            af[i] = *(const bf16x8*)&As[wm + i * 16 + lm][lq * 8];
        #pragma unroll
        for (int j = 0; j < 4; ++j)
            bfr[j] = *(const bf16x8*)&Bs[wn + j * 16 + lm][lq * 8];
        #pragma unroll
        for (int i = 0; i < 4; ++i)
            #pragma unroll
            for (int j = 0; j < 4; ++j)
                acc[i][j] = __builtin_amdgcn_mfma_f32_16x16x32_bf16(af[i], bfr[j], acc[i][j], 0, 0, 0);
    }

    // epilogue: D[row=(lane>>4)*4+r][col=lane&15]
    #pragma unroll
    for (int i = 0; i < 4; ++i) {
        const int row0 = bm + wm + i * 16 + lq * 4;
        #pragma unroll
        for (int j = 0; j < 4; ++j) {
            const int col = bn + wn + j * 16 + lm;
            const float bb = bias[col];
            #pragma unroll
            for (int r = 0; r < 4; ++r)
                C[(size_t)(row0 + r) * N + col] = acc[i][j][r] + bb;
        }
    }
}

// ---------------- RMSNorm (over full D) + interleaved RoPE, in place ----------------
__global__ __launch_bounds__(256) void k_norm_rope(
    float* __restrict__ Q, float* __restrict__ Kf,
    const float* __restrict__ qw, const float* __restrict__ kw,
    const float* __restrict__ cosb, const float* __restrict__ sinb)
{
    float* X = (blockIdx.z == 0) ? Q : Kf;
    const float* w = (blockIdx.z == 0) ? qw : kw;
    const int row = blockIdx.x;
    const int t = threadIdx.x;
    const size_t base = (size_t)row * D_DIM + t * 8;

    float x[8];
    { float4 a = *(const float4*)(X + base); float4 b = *(const float4*)(X + base + 4);
      x[0]=a.x; x[1]=a.y; x[2]=a.z; x[3]=a.w; x[4]=b.x; x[5]=b.y; x[6]=b.z; x[7]=b.w; }

    float ss = 0.f;
    #pragma unroll
    for (int i = 0; i < 8; ++i) ss += x[i] * x[i];
    #pragma unroll
    for (int off = 32; off; off >>= 1) ss += __shfl_xor(ss, off);
    __shared__ float red[4];
    if ((t & 63) == 0) red[t >> 6] = ss;
    __syncthreads();
    const float tot = red[0] + red[1] + red[2] + red[3];
    const float rms = rsqrtf(tot * (1.0f / D_DIM) + 1e-6f);

    float wv[8], c[8], sn[8];
    { float4 a = *(const float4*)(w + t * 8); float4 b = *(const float4*)(w + t * 8 + 4);
      wv[0]=a.x; wv[1]=a.y; wv[2]=a.z; wv[3]=a.w; wv[4]=b.x; wv[5]=b.y; wv[6]=b.z; wv[7]=b.w; }
    { float4 a = *(const float4*)(cosb + base); float4 b = *(const float4*)(cosb + base + 4);
      c[0]=a.x; c[1]=a.y; c[2]=a.z; c[3]=a.w; c[4]=b.x; c[5]=b.y; c[6]=b.z; c[7]=b.w; }
    { float4 a = *(const float4*)(sinb + base); float4 b = *(const float4*)(sinb + base + 4);
      sn[0]=a.x; sn[1]=a.y; sn[2]=a.z; sn[3]=a.w; sn[4]=b.x; sn[5]=b.y; sn[6]=b.z; sn[7]=b.w; }

    float out[8];
    #pragma unroll
    for (int p = 0; p < 4; ++p) {
        const float e = x[2*p]     * rms * wv[2*p];
        const float o = x[2*p + 1] * rms * wv[2*p + 1];
        out[2*p]     = e * c[2*p]     - o * sn[2*p];
        out[2*p + 1] = o * c[2*p + 1] + e * sn[2*p + 1];
    }
    float4 r0, r1;
    r0.x=out[0]; r0.y=out[1]; r0.z=out[2]; r0.w=out[3];
    r1.x=out[4]; r1.y=out[5]; r1.z=out[6]; r1.w=out[7];
    *(float4*)(X + base) = r0;
    *(float4*)(X + base + 4) = r1;
}

// ---------------- attention (non-causal, two-pass exact softmax), f32 ----------------
// Block: 16 q-rows of one head. Wave g handles rows g*4..g*4+3 across 64-key chunks.
#define QT 16
#define KT 64
#define RPT 4

__global__ __launch_bounds__(256) void k_attn(
    const float* __restrict__ Q, const float* __restrict__ K, const float* __restrict__ V,
    bf16_t* __restrict__ Ob)
{
    const int h  = blockIdx.y;
    const int q0 = blockIdx.x * QT;
    const int hc = h * DH;
    const int t  = threadIdx.x;
    const int jl  = t & 63;   // key slot (pass scores) / d slot (PV, output)
    const int grp = t >> 6;   // wave id -> row group

    __shared__ float Qs[QT][68];
    __shared__ float Ks[KT][68];
    __shared__ float Vs[KT][68];
    __shared__ float Ps[QT][65];

    for (int u = t; u < QT * DH; u += 256) {
        const int i = u >> 6, d = u & 63;
        Qs[i][d] = Q[(size_t)(q0 + i) * D_DIM + hc + d];
    }

    float m[RPT], l[RPT];
    #pragma unroll
    for (int r = 0; r < RPT; ++r) { m[r] = -1e30f; l[r] = 0.f; }
    const float scale = 0.125f;  // 1/sqrt(64)

    // pass 1: row max + exp-sum (online over chunks)
    for (int kc = 0; kc < S_LEN; kc += KT) {
        __syncthreads();
        for (int u = t; u < KT * DH; u += 256) {
            const int rr = u >> 6, d = u & 63;
            Ks[rr][d] = K[(size_t)(kc + rr) * D_DIM + hc + d];
        }
        __syncthreads();
        float s[RPT] = {0.f, 0.f, 0.f, 0.f};
        #pragma unroll
        for (int d4 = 0; d4 < DH / 4; ++d4) {
            const float4 kk = *(const float4*)&Ks[jl][d4 * 4];
            #pragma unroll
            for (int r = 0; r < RPT; ++r) {
                const float4 qq = *(const float4*)&Qs[grp * RPT + r][d4 * 4];
                s[r] += qq.x * kk.x + qq.y * kk.y + qq.z * kk.z + qq.w * kk.w;
            }
        }
        #pragma unroll
        for (int r = 0; r < RPT; ++r) {
            const float sv = s[r] * scale;
            float cmax = sv;
            for (int off = 32; off; off >>= 1) cmax = fmaxf(cmax, __shfl_xor(cmax, off));
            const float mnew = fmaxf(m[r], cmax);
            float psum = __expf(sv - mnew);
            for (int off = 32; off; off >>= 1) psum += __shfl_xor(psum, off);
            l[r] = l[r] * __expf(m[r] - mnew) + psum;
            m[r] = mnew;
        }
    }

    // pass 2: recompute scores, accumulate O
    float o[RPT] = {0.f, 0.f, 0.f, 0.f};
    for (int kc = 0; kc < S_LEN; kc += KT) {
        __syncthreads();
        for (int u = t; u < KT * DH; u += 256) {
            const int rr = u >> 6, d = u & 63;
            Ks[rr][d] = K[(size_t)(kc + rr) * D_DIM + hc + d];
            Vs[rr][d] = V[(size_t)(kc + rr) * D_DIM + hc + d];
        }
        __syncthreads();
        float s[RPT] = {0.f, 0.f, 0.f, 0.f};
        #pragma unroll
        for (int d4 = 0; d4 < DH / 4; ++d4) {
            const float4 kk = *(const float4*)&Ks[jl][d4 * 4];
            #pragma unroll
            for (int r = 0; r < RPT; ++r) {
                const float4 qq = *(const float4*)&Qs[grp * RPT + r][d4 * 4];
                s[r] += qq.x * kk.x + qq.y * kk.y + qq.z * kk.z + qq.w * kk.w;
            }
        }
        #pragma unroll
        for (int r = 0; r < RPT; ++r)
            Ps[grp * RPT + r][jl] = __expf(s[r] * scale - m[r]);
        __syncthreads();
        for (int j = 0; j < KT; ++j) {
            const float vv = Vs[j][jl];
            #pragma unroll
            for (int r = 0; r < RPT; ++r)
                o[r] += Ps[grp * RPT + r][j] * vv;
        }
    }
    #pragma unroll
    for (int r = 0; r < RPT; ++r) {
        const float inv = 1.f / l[r];
        Ob[(size_t)(q0 + grp * RPT + r) * D_DIM + hc + jl] = (bf16_t)(o[r] * inv);
    }
}

// ---------------- launcher ----------------
extern "C" void kernel_launch(void* const* d_in, const int* in_sizes, int n_in,
                              void* d_out, int out_size, void* d_ws, size_t ws_size,
                              hipStream_t stream) {
    const float* hs   = (const float*)d_in[0];
    const float* cosb = (const float*)d_in[1];
    const float* sinb = (const float*)d_in[2];
    const float* Wq   = (const float*)d_in[3];
    const float* bq   = (const float*)d_in[4];
    const float* Wk   = (const float*)d_in[5];
    const float* bk   = (const float*)d_in[6];
    const float* Wv   = (const float*)d_in[7];
    const float* bv   = (const float*)d_in[8];
    const float* qw   = (const float*)d_in[9];
    const float* kw   = (const float*)d_in[10];
    const float* Wo   = (const float*)d_in[11];
    const float* bo   = (const float*)d_in[12];
    float* out = (float*)d_out;

    char* ws = (char*)d_ws;
    bf16_t* Xb  = (bf16_t*)(ws);                       // 8 MB
    bf16_t* Wqt = (bf16_t*)(ws + ((size_t)8  << 20));  // 8 MB
    bf16_t* Wkt = (bf16_t*)(ws + ((size_t)16 << 20));
    bf16_t* Wvt = (bf16_t*)(ws + ((size_t)24 << 20));
    bf16_t* Wot = (bf16_t*)(ws + ((size_t)32 << 20));
    float*  Qf  = (float*) (ws + ((size_t)40 << 20));  // 16 MB
    float*  Kf  = (float*) (ws + ((size_t)56 << 20));
    float*  Vf  = (float*) (ws + ((size_t)72 << 20));
    bf16_t* Ab  = (bf16_t*)(ws + ((size_t)88 << 20));  // 8 MB  (total 96 MB)

    const int n = S_LEN * D_DIM;

    k_cvt_bf16<<<n / (256 * 8), 256, 0, stream>>>(hs, Xb, n);
    k_transpose_bf16<<<dim3(32, 32), 256, 0, stream>>>(Wq, Wqt);
    k_transpose_bf16<<<dim3(32, 32), 256, 0, stream>>>(Wk, Wkt);
    k_transpose_bf16<<<dim3(32, 32), 256, 0, stream>>>(Wv, Wvt);
    k_transpose_bf16<<<dim3(32, 32), 256, 0, stream>>>(Wo, Wot);

    // fused QKV projection (z selects q/k/v)
    k_gemm_bt<<<dim3(D_DIM / BN, S_LEN / BM, 3), 256, 0, stream>>>(
        Xb, Wqt, Wkt, Wvt, bq, bk, bv, Qf, Kf, Vf, S_LEN, D_DIM, D_DIM);

    // RMSNorm + RoPE in place on Q (z=0) and K (z=1)
    k_norm_rope<<<dim3(S_LEN, 1, 2), 256, 0, stream>>>(Qf, Kf, qw, kw, cosb, sinb);

    // attention -> bf16 activations for O-projection
    k_attn<<<dim3(S_LEN / QT, NHEADS), 256, 0, stream>>>(Qf, Kf, Vf, Ab);

    // output projection
    k_gemm_bt<<<dim3(D_DIM / BN, S_LEN / BM, 1), 256, 0, stream>>>(
        Ab, Wot, Wot, Wot, bo, bo, bo, out, out, out, S_LEN, D_DIM, D_DIM);
}

// Round 2
// 403.338 us; speedup vs baseline: 5.5386x; 5.5386x over previous
//
#include <hip/hip_runtime.h>
#include <hip/hip_bf16.h>

typedef __bf16 bf16_t;
typedef __bf16 bf16x8 __attribute__((ext_vector_type(8)));
typedef __bf16 bf16x4 __attribute__((ext_vector_type(4)));
typedef float floatx4 __attribute__((ext_vector_type(4)));
typedef float floatx16 __attribute__((ext_vector_type(16)));

#define S_LEN 2048
#define D_DIM 2048
#define NHEADS 32
#define DH 64

// ---------------- f32 -> bf16 elementwise convert ----------------
__global__ __launch_bounds__(256) void k_cvt_bf16(const float* __restrict__ x,
                                                  bf16_t* __restrict__ y, int n) {
    int i = (blockIdx.x * 256 + threadIdx.x) * 8;
    if (i + 8 > n) return;
    const float4 a = *(const float4*)(x + i);
    const float4 b = *(const float4*)(x + i + 4);
    bf16x8 o;
    o[0] = (bf16_t)a.x; o[1] = (bf16_t)a.y; o[2] = (bf16_t)a.z; o[3] = (bf16_t)a.w;
    o[4] = (bf16_t)b.x; o[5] = (bf16_t)b.y; o[6] = (bf16_t)b.z; o[7] = (bf16_t)b.w;
    *(bf16x8*)(y + i) = o;
}

// ---------------- W[k][n] f32 -> Wt[n][k] bf16 ----------------
__global__ __launch_bounds__(256) void k_transpose_bf16(const float* __restrict__ W,
                                                        bf16_t* __restrict__ Wt) {
    __shared__ float tile[64][65];
    const int n0 = blockIdx.x * 64, k0 = blockIdx.y * 64;
    const int tx = threadIdx.x & 63, ty = threadIdx.x >> 6;
    #pragma unroll
    for (int i = 0; i < 16; ++i) {
        int r = i * 4 + ty;
        tile[r][tx] = W[(size_t)(k0 + r) * D_DIM + n0 + tx];
    }
    __syncthreads();
    #pragma unroll
    for (int i = 0; i < 16; ++i) {
        int r = i * 4 + ty;  // n index within tile
        Wt[(size_t)(n0 + r) * D_DIM + k0 + tx] = (bf16_t)tile[tx][r];
    }
}

// ---------------- GEMM: C[m][n] = sum_k A[m][k]*Bt[n][k] + bias[n] ----------------
// z==0/1: f32 output C0/C1.  z==2: bf16 TRANSPOSED output Vt[n][m] (per-head V layout).
#define BM 128
#define BN 128
#define BK 32
#define LDK 40

__global__ __launch_bounds__(256) void k_gemm_bt(
    const bf16_t* __restrict__ A,
    const bf16_t* __restrict__ Bt0, const bf16_t* __restrict__ Bt1, const bf16_t* __restrict__ Bt2,
    const float* __restrict__ bias0, const float* __restrict__ bias1, const float* __restrict__ bias2,
    float* __restrict__ C0, float* __restrict__ C1, bf16_t* __restrict__ VtOut,
    int M, int N, int K)
{
    const bf16_t* Bt; const float* bias;
    if (blockIdx.z == 0)      { Bt = Bt0; bias = bias0; }
    else if (blockIdx.z == 1) { Bt = Bt1; bias = bias1; }
    else                      { Bt = Bt2; bias = bias2; }

    __shared__ bf16_t As[BM][LDK];
    __shared__ bf16_t Bs[BN][LDK];

    const int t    = threadIdx.x;
    const int lane = t & 63;
    const int wave = t >> 6;
    const int wm = (wave >> 1) * 64;
    const int wn = (wave & 1) * 64;
    const int bm = blockIdx.y * BM;
    const int bn = blockIdx.x * BN;
    const int lm = lane & 15;
    const int lq = lane >> 4;

    const int sr = t >> 1;
    const int sc = (t & 1) * 16;

    floatx4 acc[4][4];
    #pragma unroll
    for (int i = 0; i < 4; ++i)
        #pragma unroll
        for (int j = 0; j < 4; ++j)
            #pragma unroll
            for (int r = 0; r < 4; ++r) acc[i][j][r] = 0.f;

    const bf16_t* Aptr = A  + (size_t)(bm + sr) * K + sc;
    const bf16_t* Bptr = Bt + (size_t)(bn + sr) * K + sc;

    for (int k0 = 0; k0 < K; k0 += BK) {
        const uint4 av0 = *(const uint4*)(Aptr + k0);
        const uint4 av1 = *(const uint4*)(Aptr + k0 + 8);
        const uint4 bv0 = *(const uint4*)(Bptr + k0);
        const uint4 bv1 = *(const uint4*)(Bptr + k0 + 8);
        __syncthreads();
        *(uint4*)&As[sr][sc]     = av0;
        *(uint4*)&As[sr][sc + 8] = av1;
        *(uint4*)&Bs[sr][sc]     = bv0;
        *(uint4*)&Bs[sr][sc + 8] = bv1;
        __syncthreads();

        bf16x8 af[4], bfr[4];
        #pragma unroll
        for (int i = 0; i < 4; ++i)
            af[i] = *(const bf16x8*)&As[wm + i * 16 + lm][lq * 8];
        #pragma unroll
        for (int j = 0; j < 4; ++j)
            bfr[j] = *(const bf16x8*)&Bs[wn + j * 16 + lm][lq * 8];
        #pragma unroll
        for (int i = 0; i < 4; ++i)
            #pragma unroll
            for (int j = 0; j < 4; ++j)
                acc[i][j] = __builtin_amdgcn_mfma_f32_16x16x32_bf16(af[i], bfr[j], acc[i][j], 0, 0, 0);
    }

    if (blockIdx.z == 2) {
        // V: write bf16 transposed Vt[n][m] (n = h*64+d, m = s); 4 consecutive m per frag
        #pragma unroll
        for (int i = 0; i < 4; ++i) {
            const int row0 = bm + wm + i * 16 + lq * 4;
            #pragma unroll
            for (int j = 0; j < 4; ++j) {
                const int col = bn + wn + j * 16 + lm;
                const float bb = bias[col];
                bf16x4 pk;
                #pragma unroll
                for (int r = 0; r < 4; ++r) pk[r] = (bf16_t)(acc[i][j][r] + bb);
                *(bf16x4*)(VtOut + (size_t)col * M + row0) = pk;
            }
        }
    } else {
        float* C = (blockIdx.z == 0) ? C0 : C1;
        #pragma unroll
        for (int i = 0; i < 4; ++i) {
            const int row0 = bm + wm + i * 16 + lq * 4;
            #pragma unroll
            for (int j = 0; j < 4; ++j) {
                const int col = bn + wn + j * 16 + lm;
                const float bb = bias[col];
                #pragma unroll
                for (int r = 0; r < 4; ++r)
                    C[(size_t)(row0 + r) * N + col] = acc[i][j][r] + bb;
            }
        }
    }
}

// ---------------- RMSNorm (full D) + interleaved RoPE -> bf16 ----------------
__global__ __launch_bounds__(256) void k_norm_rope(
    const float* __restrict__ Qf, const float* __restrict__ Kf,
    bf16_t* __restrict__ Qb, bf16_t* __restrict__ Kb,
    const float* __restrict__ qw, const float* __restrict__ kw,
    const float* __restrict__ cosb, const float* __restrict__ sinb)
{
    const float* X = (blockIdx.z == 0) ? Qf : Kf;
    bf16_t* Y = (blockIdx.z == 0) ? Qb : Kb;
    const float* w = (blockIdx.z == 0) ? qw : kw;
    const int row = blockIdx.x;
    const int t = threadIdx.x;
    const size_t base = (size_t)row * D_DIM + t * 8;

    float x[8];
    { float4 a = *(const float4*)(X + base); float4 b = *(const float4*)(X + base + 4);
      x[0]=a.x; x[1]=a.y; x[2]=a.z; x[3]=a.w; x[4]=b.x; x[5]=b.y; x[6]=b.z; x[7]=b.w; }

    float ss = 0.f;
    #pragma unroll
    for (int i = 0; i < 8; ++i) ss += x[i] * x[i];
    #pragma unroll
    for (int off = 32; off; off >>= 1) ss += __shfl_xor(ss, off);
    __shared__ float red[4];
    if ((t & 63) == 0) red[t >> 6] = ss;
    __syncthreads();
    const float tot = red[0] + red[1] + red[2] + red[3];
    const float rms = rsqrtf(tot * (1.0f / D_DIM) + 1e-6f);

    float wv[8], c[8], sn[8];
    { float4 a = *(const float4*)(w + t * 8); float4 b = *(const float4*)(w + t * 8 + 4);
      wv[0]=a.x; wv[1]=a.y; wv[2]=a.z; wv[3]=a.w; wv[4]=b.x; wv[5]=b.y; wv[6]=b.z; wv[7]=b.w; }
    { float4 a = *(const float4*)(cosb + base); float4 b = *(const float4*)(cosb + base + 4);
      c[0]=a.x; c[1]=a.y; c[2]=a.z; c[3]=a.w; c[4]=b.x; c[5]=b.y; c[6]=b.z; c[7]=b.w; }
    { float4 a = *(const float4*)(sinb + base); float4 b = *(const float4*)(sinb + base + 4);
      sn[0]=a.x; sn[1]=a.y; sn[2]=a.z; sn[3]=a.w; sn[4]=b.x; sn[5]=b.y; sn[6]=b.z; sn[7]=b.w; }

    bf16x8 o;
    #pragma unroll
    for (int p = 0; p < 4; ++p) {
        const float e = x[2*p]     * rms * wv[2*p];
        const float od = x[2*p + 1] * rms * wv[2*p + 1];
        o[2*p]     = (bf16_t)(e * c[2*p]     - od * sn[2*p]);
        o[2*p + 1] = (bf16_t)(od * c[2*p + 1] + e * sn[2*p + 1]);
    }
    *(bf16x8*)(Y + base) = o;
}

// ---------------- MFMA flash attention (non-causal, no-max softmax) ----------------
// Block: head h, 128 q rows (4 waves x 32). K-chunks of 64.
// mfma_f32_32x32x16_bf16: A/B: m|n=lane&31, k=(lane>>5)*8+j. C/D: col=lane&31,
// row=(reg&3)+8*(reg>>2)+4*(lane>>5).
#define LDP 72

__global__ __launch_bounds__(256) void k_flash(
    const bf16_t* __restrict__ Qb, const bf16_t* __restrict__ Kb,
    const bf16_t* __restrict__ Vt, bf16_t* __restrict__ Ob)
{
    const int h = blockIdx.y, hc = h * DH;
    const int t = threadIdx.x;
    const int wave = t >> 6, lane = t & 63;
    const int ln = lane & 31, hf = lane >> 5;
    const int qw = blockIdx.x * 128 + wave * 32;

    __shared__ bf16_t Ks[64][LDP];          // [key][dh]
    __shared__ bf16_t Vs[64][LDP];          // [d][key]
    __shared__ bf16_t Ps[4][32][LDP];       // per-wave [q][key]

    // Q A-fragments in registers for the whole kernel
    bf16x8 aq[4];
    #pragma unroll
    for (int kt = 0; kt < 4; ++kt)
        aq[kt] = *(const bf16x8*)(Qb + (size_t)(qw + ln) * D_DIM + hc + kt * 16 + hf * 8);

    floatx16 o0, o1, lf;
    #pragma unroll
    for (int r = 0; r < 16; ++r) { o0[r] = 0.f; o1[r] = 0.f; lf[r] = 0.f; }

    bf16x8 ones;
    #pragma unroll
    for (int j = 0; j < 8; ++j) ones[j] = (bf16_t)1.0f;

    const int sr = t >> 2;           // 0..63
    const int sc = (t & 3) * 16;     // 0,16,32,48
    const bf16_t* kg = Kb + (size_t)sr * D_DIM + hc + sc;
    const bf16_t* vg = Vt + (size_t)(hc + sr) * S_LEN + sc;

    for (int kc = 0; kc < S_LEN; kc += 64) {
        const uint4 k0v = *(const uint4*)(kg + (size_t)kc * D_DIM);
        const uint4 k1v = *(const uint4*)(kg + (size_t)kc * D_DIM + 8);
        const uint4 v0v = *(const uint4*)(vg + kc);
        const uint4 v1v = *(const uint4*)(vg + kc + 8);
        __syncthreads();               // prior chunk's Ks/Vs reads done
        *(uint4*)&Ks[sr][sc]     = k0v;
        *(uint4*)&Ks[sr][sc + 8] = k1v;
        *(uint4*)&Vs[sr][sc]     = v0v;
        *(uint4*)&Vs[sr][sc + 8] = v1v;
        __syncthreads();

        // S = Q K^T : 32q x 64keys per wave
        floatx16 s0, s1;
        #pragma unroll
        for (int r = 0; r < 16; ++r) { s0[r] = 0.f; s1[r] = 0.f; }
        #pragma unroll
        for (int kt = 0; kt < 4; ++kt) {
            const bf16x8 b0 = *(const bf16x8*)&Ks[ln][kt * 16 + hf * 8];
            const bf16x8 b1 = *(const bf16x8*)&Ks[32 + ln][kt * 16 + hf * 8];
            s0 = __builtin_amdgcn_mfma_f32_32x32x16_bf16(aq[kt], b0, s0, 0, 0, 0);
            s1 = __builtin_amdgcn_mfma_f32_32x32x16_bf16(aq[kt], b1, s1, 0, 0, 0);
        }

        // P = exp(s/8) -> bf16 LDS (C-layout -> [q][key] transpose)
        #pragma unroll
        for (int r = 0; r < 16; ++r) {
            const int row = (r & 3) + 8 * (r >> 2) + 4 * hf;
            Ps[wave][row][ln]      = (bf16_t)__expf(s0[r] * 0.125f);
            Ps[wave][row][32 + ln] = (bf16_t)__expf(s1[r] * 0.125f);
        }
        __syncthreads();               // make transposed P visible across lanes

        // O += P V ; l += P * ones
        #pragma unroll
        for (int kt = 0; kt < 4; ++kt) {
            const bf16x8 ap  = *(const bf16x8*)&Ps[wave][ln][kt * 16 + hf * 8];
            const bf16x8 bv0 = *(const bf16x8*)&Vs[ln][kt * 16 + hf * 8];
            const bf16x8 bv1 = *(const bf16x8*)&Vs[32 + ln][kt * 16 + hf * 8];
            o0 = __builtin_amdgcn_mfma_f32_32x32x16_bf16(ap, bv0, o0, 0, 0, 0);
            o1 = __builtin_amdgcn_mfma_f32_32x32x16_bf16(ap, bv1, o1, 0, 0, 0);
            lf = __builtin_amdgcn_mfma_f32_32x32x16_bf16(ap, ones, lf, 0, 0, 0);
        }
    }

    #pragma unroll
    for (int r = 0; r < 16; ++r) {
        const int row = (r & 3) + 8 * (r >> 2) + 4 * hf;
        const float inv = 1.0f / lf[r];
        Ob[(size_t)(qw + row) * D_DIM + hc + ln]      = (bf16_t)(o0[r] * inv);
        Ob[(size_t)(qw + row) * D_DIM + hc + 32 + ln] = (bf16_t)(o1[r] * inv);
    }
}

// ---------------- launcher ----------------
extern "C" void kernel_launch(void* const* d_in, const int* in_sizes, int n_in,
                              void* d_out, int out_size, void* d_ws, size_t ws_size,
                              hipStream_t stream) {
    const float* hs   = (const float*)d_in[0];
    const float* cosb = (const float*)d_in[1];
    const float* sinb = (const float*)d_in[2];
    const float* Wq   = (const float*)d_in[3];
    const float* bq   = (const float*)d_in[4];
    const float* Wk   = (const float*)d_in[5];
    const float* bk   = (const float*)d_in[6];
    const float* Wv   = (const float*)d_in[7];
    const float* bv   = (const float*)d_in[8];
    const float* qw   = (const float*)d_in[9];
    const float* kw   = (const float*)d_in[10];
    const float* Wo   = (const float*)d_in[11];
    const float* bo   = (const float*)d_in[12];
    float* out = (float*)d_out;

    char* ws = (char*)d_ws;
    bf16_t* Xb  = (bf16_t*)(ws);                       // 0-8 MB   (later aliased by Qb)
    bf16_t* Wqt = (bf16_t*)(ws + ((size_t)8  << 20));  // 8-16     (later aliased by Kb)
    bf16_t* Wkt = (bf16_t*)(ws + ((size_t)16 << 20));  // 16-24    (later aliased by Ob)
    bf16_t* Wvt = (bf16_t*)(ws + ((size_t)24 << 20));  // 24-32
    bf16_t* Wot = (bf16_t*)(ws + ((size_t)32 << 20));  // 32-40
    float*  Qf  = (float*) (ws + ((size_t)40 << 20));  // 40-56
    float*  Kf  = (float*) (ws + ((size_t)56 << 20));  // 56-72
    bf16_t* Vt  = (bf16_t*)(ws + ((size_t)72 << 20));  // 72-80  (per-head transposed V)
    bf16_t* Qb  = (bf16_t*)(ws);                       // alias Xb (Xb dead after QKV GEMM)
    bf16_t* Kb  = (bf16_t*)(ws + ((size_t)8  << 20));  // alias Wqt
    bf16_t* Ob  = (bf16_t*)(ws + ((size_t)16 << 20));  // alias Wkt

    const int n = S_LEN * D_DIM;

    k_cvt_bf16<<<n / (256 * 8), 256, 0, stream>>>(hs, Xb, n);
    k_transpose_bf16<<<dim3(32, 32), 256, 0, stream>>>(Wq, Wqt);
    k_transpose_bf16<<<dim3(32, 32), 256, 0, stream>>>(Wk, Wkt);
    k_transpose_bf16<<<dim3(32, 32), 256, 0, stream>>>(Wv, Wvt);
    k_transpose_bf16<<<dim3(32, 32), 256, 0, stream>>>(Wo, Wot);

    // QKV projection: Q,K f32; V -> bf16 per-head transposed Vt
    k_gemm_bt<<<dim3(D_DIM / BN, S_LEN / BM, 3), 256, 0, stream>>>(
        Xb, Wqt, Wkt, Wvt, bq, bk, bv, Qf, Kf, Vt, S_LEN, D_DIM, D_DIM);

    // RMSNorm + RoPE -> bf16
    k_norm_rope<<<dim3(S_LEN, 1, 2), 256, 0, stream>>>(Qf, Kf, Qb, Kb, qw, kw, cosb, sinb);

    // MFMA flash attention -> bf16 activations
    k_flash<<<dim3(S_LEN / 128, NHEADS), 256, 0, stream>>>(Qb, Kb, Vt, Ob);

    // output projection
    k_gemm_bt<<<dim3(D_DIM / BN, S_LEN / BM, 1), 256, 0, stream>>>(
        Ob, Wot, Wot, Wot, bo, bo, bo, out, out, (bf16_t*)nullptr, S_LEN, D_DIM, D_DIM);
}

// Round 3
// 370.775 us; speedup vs baseline: 6.0250x; 1.0878x over previous
//
#include <hip/hip_runtime.h>
#include <hip/hip_bf16.h>

typedef __bf16 bf16_t;
typedef __bf16 bf16x8 __attribute__((ext_vector_type(8)));
typedef __bf16 bf16x4 __attribute__((ext_vector_type(4)));
typedef float floatx4 __attribute__((ext_vector_type(4)));
typedef float floatx16 __attribute__((ext_vector_type(16)));

#define S_LEN 2048
#define D_DIM 2048
#define NHEADS 32
#define DH 64

// async global->LDS, 16B per lane; LDS dest = wave-uniform base + lane*16
__device__ __forceinline__ void gll16(const bf16_t* g, bf16_t* l) {
    __builtin_amdgcn_global_load_lds(
        (const __attribute__((address_space(1))) unsigned int*)g,
        (__attribute__((address_space(3))) unsigned int*)l, 16, 0, 0);
}

// ---------------- f32 -> bf16 elementwise convert ----------------
__global__ __launch_bounds__(256) void k_cvt_bf16(const float* __restrict__ x,
                                                  bf16_t* __restrict__ y, int n) {
    int i = (blockIdx.x * 256 + threadIdx.x) * 8;
    if (i + 8 > n) return;
    const float4 a = *(const float4*)(x + i);
    const float4 b = *(const float4*)(x + i + 4);
    bf16x8 o;
    o[0] = (bf16_t)a.x; o[1] = (bf16_t)a.y; o[2] = (bf16_t)a.z; o[3] = (bf16_t)a.w;
    o[4] = (bf16_t)b.x; o[5] = (bf16_t)b.y; o[6] = (bf16_t)b.z; o[7] = (bf16_t)b.w;
    *(bf16x8*)(y + i) = o;
}

// ---------------- 4x weight transpose W[k][n] f32 -> Wt[n][k] bf16 ----------------
__global__ __launch_bounds__(256) void k_transpose4(
    const float* __restrict__ W0, const float* __restrict__ W1,
    const float* __restrict__ W2, const float* __restrict__ W3,
    bf16_t* __restrict__ T0, bf16_t* __restrict__ T1,
    bf16_t* __restrict__ T2, bf16_t* __restrict__ T3)
{
    const float* W; bf16_t* T;
    switch (blockIdx.z) {
        case 0: W = W0; T = T0; break;
        case 1: W = W1; T = T1; break;
        case 2: W = W2; T = T2; break;
        default: W = W3; T = T3; break;
    }
    __shared__ float tile[64][65];
    const int n0 = blockIdx.x * 64, k0 = blockIdx.y * 64;
    const int tx = threadIdx.x & 63, ty = threadIdx.x >> 6;
    #pragma unroll
    for (int i = 0; i < 16; ++i) {
        int r = i * 4 + ty;
        tile[r][tx] = W[(size_t)(k0 + r) * D_DIM + n0 + tx];
    }
    __syncthreads();
    #pragma unroll
    for (int i = 0; i < 16; ++i) {
        int r = i * 4 + ty;
        T[(size_t)(n0 + r) * D_DIM + k0 + tx] = (bf16_t)tile[tx][r];
    }
}

// ---------------- GEMM: C[m][n] = sum_k A[m][k]*Bt[n][k] + bias[n] ----------------
// global_load_lds staging, unpadded LDS with XOR swizzle chunk'=chunk^((row>>1)&3).
// z==0/1: f32 output. z==2: bf16 transposed output Vt[n][m].
#define BM 128
#define BN 128
#define BK 32

__global__ __launch_bounds__(256) void k_gemm_bt(
    const bf16_t* __restrict__ A,
    const bf16_t* __restrict__ Bt0, const bf16_t* __restrict__ Bt1, const bf16_t* __restrict__ Bt2,
    const float* __restrict__ bias0, const float* __restrict__ bias1, const float* __restrict__ bias2,
    float* __restrict__ C0, float* __restrict__ C1, bf16_t* __restrict__ VtOut,
    int M, int N, int K)
{
    const bf16_t* Bt; const float* bias;
    if (blockIdx.z == 0)      { Bt = Bt0; bias = bias0; }
    else if (blockIdx.z == 1) { Bt = Bt1; bias = bias1; }
    else                      { Bt = Bt2; bias = bias2; }

    __shared__ bf16_t As[BM][BK];   // 8 KB, swizzled
    __shared__ bf16_t Bs[BN][BK];   // 8 KB, swizzled

    const int t    = threadIdx.x;
    const int lane = t & 63;
    const int wave = t >> 6;
    const int wm = (wave >> 1) * 64;
    const int wn = (wave & 1) * 64;
    const int bm = blockIdx.y * BM;
    const int bn = blockIdx.x * BN;
    const int lm = lane & 15;
    const int lq = lane >> 4;

    // staging: wave w covers rows w*32..w*32+31; each gll16 covers 16 rows (4 lanes/row)
    const int srow0 = wave * 32 + (lane >> 2);
    const int srow1 = srow0 + 16;
    const int cp    = lane & 3;
    const int gc0 = cp ^ ((srow0 >> 1) & 3);
    const int gc1 = cp ^ ((srow1 >> 1) & 3);

    const bf16_t* Ag0 = A  + (size_t)(bm + srow0) * K + gc0 * 8;
    const bf16_t* Ag1 = A  + (size_t)(bm + srow1) * K + gc1 * 8;
    const bf16_t* Bg0 = Bt + (size_t)(bn + srow0) * K + gc0 * 8;
    const bf16_t* Bg1 = Bt + (size_t)(bn + srow1) * K + gc1 * 8;
    bf16_t* Al0 = &As[wave * 32][0];
    bf16_t* Al1 = &As[wave * 32 + 16][0];
    bf16_t* Bl0 = &Bs[wave * 32][0];
    bf16_t* Bl1 = &Bs[wave * 32 + 16][0];

    floatx4 acc[4][4];
    #pragma unroll
    for (int i = 0; i < 4; ++i)
        #pragma unroll
        for (int j = 0; j < 4; ++j)
            #pragma unroll
            for (int r = 0; r < 4; ++r) acc[i][j][r] = 0.f;

    for (int k0 = 0; k0 < K; k0 += BK) {
        __syncthreads();  // prior iter's fragment reads done
        gll16(Ag0 + k0, Al0);
        gll16(Ag1 + k0, Al1);
        gll16(Bg0 + k0, Bl0);
        gll16(Bg1 + k0, Bl1);
        __syncthreads();  // drains vmcnt -> staged data visible

        bf16x8 af[4], bfr[4];
        #pragma unroll
        for (int i = 0; i < 4; ++i) {
            const int row = wm + i * 16 + lm;
            af[i] = *(const bf16x8*)&As[row][(lq ^ ((row >> 1) & 3)) * 8];
        }
        #pragma unroll
        for (int j = 0; j < 4; ++j) {
            const int row = wn + j * 16 + lm;
            bfr[j] = *(const bf16x8*)&Bs[row][(lq ^ ((row >> 1) & 3)) * 8];
        }
        #pragma unroll
        for (int i = 0; i < 4; ++i)
            #pragma unroll
            for (int j = 0; j < 4; ++j)
                acc[i][j] = __builtin_amdgcn_mfma_f32_16x16x32_bf16(af[i], bfr[j], acc[i][j], 0, 0, 0);
    }

    if (blockIdx.z == 2) {
        #pragma unroll
        for (int i = 0; i < 4; ++i) {
            const int row0 = bm + wm + i * 16 + lq * 4;
            #pragma unroll
            for (int j = 0; j < 4; ++j) {
                const int col = bn + wn + j * 16 + lm;
                const float bb = bias[col];
                bf16x4 pk;
                #pragma unroll
                for (int r = 0; r < 4; ++r) pk[r] = (bf16_t)(acc[i][j][r] + bb);
                *(bf16x4*)(VtOut + (size_t)col * M + row0) = pk;
            }
        }
    } else {
        float* C = (blockIdx.z == 0) ? C0 : C1;
        #pragma unroll
        for (int i = 0; i < 4; ++i) {
            const int row0 = bm + wm + i * 16 + lq * 4;
            #pragma unroll
            for (int j = 0; j < 4; ++j) {
                const int col = bn + wn + j * 16 + lm;
                const float bb = bias[col];
                #pragma unroll
                for (int r = 0; r < 4; ++r)
                    C[(size_t)(row0 + r) * N + col] = acc[i][j][r] + bb;
            }
        }
    }
}

// ---------------- RMSNorm (full D) + interleaved RoPE -> bf16 ----------------
__global__ __launch_bounds__(256) void k_norm_rope(
    const float* __restrict__ Qf, const float* __restrict__ Kf,
    bf16_t* __restrict__ Qb, bf16_t* __restrict__ Kb,
    const float* __restrict__ qw, const float* __restrict__ kw,
    const float* __restrict__ cosb, const float* __restrict__ sinb)
{
    const float* X = (blockIdx.z == 0) ? Qf : Kf;
    bf16_t* Y = (blockIdx.z == 0) ? Qb : Kb;
    const float* w = (blockIdx.z == 0) ? qw : kw;
    const int row = blockIdx.x;
    const int t = threadIdx.x;
    const size_t base = (size_t)row * D_DIM + t * 8;

    float x[8];
    { float4 a = *(const float4*)(X + base); float4 b = *(const float4*)(X + base + 4);
      x[0]=a.x; x[1]=a.y; x[2]=a.z; x[3]=a.w; x[4]=b.x; x[5]=b.y; x[6]=b.z; x[7]=b.w; }

    float ss = 0.f;
    #pragma unroll
    for (int i = 0; i < 8; ++i) ss += x[i] * x[i];
    #pragma unroll
    for (int off = 32; off; off >>= 1) ss += __shfl_xor(ss, off);
    __shared__ float red[4];
    if ((t & 63) == 0) red[t >> 6] = ss;
    __syncthreads();
    const float tot = red[0] + red[1] + red[2] + red[3];
    const float rms = rsqrtf(tot * (1.0f / D_DIM) + 1e-6f);

    float wv[8], c[8], sn[8];
    { float4 a = *(const float4*)(w + t * 8); float4 b = *(const float4*)(w + t * 8 + 4);
      wv[0]=a.x; wv[1]=a.y; wv[2]=a.z; wv[3]=a.w; wv[4]=b.x; wv[5]=b.y; wv[6]=b.z; wv[7]=b.w; }
    { float4 a = *(const float4*)(cosb + base); float4 b = *(const float4*)(cosb + base + 4);
      c[0]=a.x; c[1]=a.y; c[2]=a.z; c[3]=a.w; c[4]=b.x; c[5]=b.y; c[6]=b.z; c[7]=b.w; }
    { float4 a = *(const float4*)(sinb + base); float4 b = *(const float4*)(sinb + base + 4);
      sn[0]=a.x; sn[1]=a.y; sn[2]=a.z; sn[3]=a.w; sn[4]=b.x; sn[5]=b.y; sn[6]=b.z; sn[7]=b.w; }

    bf16x8 o;
    #pragma unroll
    for (int p = 0; p < 4; ++p) {
        const float e  = x[2*p]     * rms * wv[2*p];
        const float od = x[2*p + 1] * rms * wv[2*p + 1];
        o[2*p]     = (bf16_t)(e * c[2*p]     - od * sn[2*p]);
        o[2*p + 1] = (bf16_t)(od * c[2*p + 1] + e * sn[2*p + 1]);
    }
    *(bf16x8*)(Y + base) = o;
}

// ---------------- MFMA flash attention (non-causal, no-max softmax) ----------------
// Computes S^T = K*Q^T so P lands with col=q, row=key -> packed b64 P writes.
// K/V staged via global_load_lds into unpadded [64][64] with chunk'=c^(row&7) swizzle.
#define LDPQ 72

__global__ __launch_bounds__(256) void k_flash(
    const bf16_t* __restrict__ Qb, const bf16_t* __restrict__ Kb,
    const bf16_t* __restrict__ Vt, bf16_t* __restrict__ Ob)
{
    const int h = blockIdx.y, hc = h * DH;
    const int t = threadIdx.x;
    const int wave = t >> 6, lane = t & 63;
    const int ln = lane & 31, hf = lane >> 5;
    const int qw = blockIdx.x * 128 + wave * 32;

    __shared__ bf16_t Ks[64][64];        // [key][dh], swizzled
    __shared__ bf16_t Vs[64][64];        // [d][key],  swizzled
    __shared__ bf16_t Ps[4][32][LDPQ];   // per-wave [q][key]

    // Q B-fragments (n=q, k=dh) in registers for the whole kernel
    bf16x8 bq[4];
    #pragma unroll
    for (int kt = 0; kt < 4; ++kt)
        bq[kt] = *(const bf16x8*)(Qb + (size_t)(qw + ln) * D_DIM + hc + kt * 16 + hf * 8);

    // staging: wave covers 16 rows of K and V (2 gll each, 8 rows/instr)
    const int r0  = wave * 16 + (lane >> 3);
    const int r1  = r0 + 8;
    const int cp8 = lane & 7;
    const int gc0 = cp8 ^ (r0 & 7);
    const int gc1 = cp8 ^ (r1 & 7);
    const bf16_t* kg0 = Kb + (size_t)r0 * D_DIM + hc + gc0 * 8;
    const bf16_t* kg1 = Kb + (size_t)r1 * D_DIM + hc + gc1 * 8;
    const bf16_t* vg0 = Vt + (size_t)(hc + r0) * S_LEN + gc0 * 8;
    const bf16_t* vg1 = Vt + (size_t)(hc + r1) * S_LEN + gc1 * 8;
    bf16_t* kl0 = &Ks[wave * 16][0];
    bf16_t* kl1 = &Ks[wave * 16 + 8][0];
    bf16_t* vl0 = &Vs[wave * 16][0];
    bf16_t* vl1 = &Vs[wave * 16 + 8][0];

    floatx16 o0, o1, lf;
    #pragma unroll
    for (int r = 0; r < 16; ++r) { o0[r] = 0.f; o1[r] = 0.f; lf[r] = 0.f; }

    bf16x8 ones;
    #pragma unroll
    for (int j = 0; j < 8; ++j) ones[j] = (bf16_t)1.0f;

    const int swz = ln & 7;  // row-swizzle term for this lane's frag reads
    const float c_exp = 0.125f * 1.44269504089f;  // 1/sqrt(64) * log2(e)

    for (int kc = 0; kc < S_LEN; kc += 64) {
        __syncthreads();  // prior chunk's Ks/Vs reads done
        gll16(kg0 + (size_t)kc * D_DIM, kl0);
        gll16(kg1 + (size_t)kc * D_DIM, kl1);
        gll16(vg0 + kc, vl0);
        gll16(vg1 + kc, vl1);
        __syncthreads();  // vmcnt drained

        // S^T = K . Q^T : A[m=key][k=dh] from Ks, B[n=q][k=dh] = bq
        floatx16 st0, st1;
        #pragma unroll
        for (int r = 0; r < 16; ++r) { st0[r] = 0.f; st1[r] = 0.f; }
        #pragma unroll
        for (int kt = 0; kt < 4; ++kt) {
            const int ch = 2 * kt + hf;                 // 16B chunk of dh dim
            const bf16x8 a0 = *(const bf16x8*)&Ks[ln]     [(ch ^ swz) * 8];
            const bf16x8 a1 = *(const bf16x8*)&Ks[32 + ln][(ch ^ swz) * 8];
            st0 = __builtin_amdgcn_mfma_f32_32x32x16_bf16(a0, bq[kt], st0, 0, 0, 0);
            st1 = __builtin_amdgcn_mfma_f32_32x32x16_bf16(a1, bq[kt], st1, 0, 0, 0);
        }

        // P^T C-layout: col=q(=ln), row=key=(r&3)+8*(r>>2)+4*hf -> packed b64 writes
        #pragma unroll
        for (int g = 0; g < 4; ++g) {
            bf16x4 p0, p1;
            #pragma unroll
            for (int r4 = 0; r4 < 4; ++r4) {
                p0[r4] = (bf16_t)__builtin_amdgcn_exp2f(st0[4 * g + r4] * c_exp);
                p1[r4] = (bf16_t)__builtin_amdgcn_exp2f(st1[4 * g + r4] * c_exp);
            }
            *(bf16x4*)&Ps[wave][ln][8 * g + 4 * hf]      = p0;
            *(bf16x4*)&Ps[wave][ln][32 + 8 * g + 4 * hf] = p1;
        }
        // wave-private LDS round-trip: in-order DS pipe + explicit drain, no barrier
        asm volatile("s_waitcnt lgkmcnt(0)" ::: "memory");

        // O += P V ; l += P * 1   (A[m=q][k=key], B[n=d][k=key])
        #pragma unroll
        for (int kt = 0; kt < 4; ++kt) {
            const int ch = 2 * kt + hf;
            const bf16x8 ap  = *(const bf16x8*)&Ps[wave][ln][kt * 16 + hf * 8];
            const bf16x8 bv0 = *(const bf16x8*)&Vs[ln]     [(ch ^ swz) * 8];
            const bf16x8 bv1 = *(const bf16x8*)&Vs[32 + ln][(ch ^ swz) * 8];
            o0 = __builtin_amdgcn_mfma_f32_32x32x16_bf16(ap, bv0, o0, 0, 0, 0);
            o1 = __builtin_amdgcn_mfma_f32_32x32x16_bf16(ap, bv1, o1, 0, 0, 0);
            lf = __builtin_amdgcn_mfma_f32_32x32x16_bf16(ap, ones, lf, 0, 0, 0);
        }
    }

    #pragma unroll
    for (int r = 0; r < 16; ++r) {
        const int row = (r & 3) + 8 * (r >> 2) + 4 * hf;   // q
        const float inv = 1.0f / lf[r];
        Ob[(size_t)(qw + row) * D_DIM + hc + ln]      = (bf16_t)(o0[r] * inv);
        Ob[(size_t)(qw + row) * D_DIM + hc + 32 + ln] = (bf16_t)(o1[r] * inv);
    }
}

// ---------------- launcher ----------------
extern "C" void kernel_launch(void* const* d_in, const int* in_sizes, int n_in,
                              void* d_out, int out_size, void* d_ws, size_t ws_size,
                              hipStream_t stream) {
    const float* hs   = (const float*)d_in[0];
    const float* cosb = (const float*)d_in[1];
    const float* sinb = (const float*)d_in[2];
    const float* Wq   = (const float*)d_in[3];
    const float* bq   = (const float*)d_in[4];
    const float* Wk   = (const float*)d_in[5];
    const float* bk   = (const float*)d_in[6];
    const float* Wv   = (const float*)d_in[7];
    const float* bv   = (const float*)d_in[8];
    const float* qw   = (const float*)d_in[9];
    const float* kw   = (const float*)d_in[10];
    const float* Wo   = (const float*)d_in[11];
    const float* bo   = (const float*)d_in[12];
    float* out = (float*)d_out;

    char* ws = (char*)d_ws;
    bf16_t* Xb  = (bf16_t*)(ws);                       // 0-8 MB   (aliased by Qb later)
    bf16_t* Wqt = (bf16_t*)(ws + ((size_t)8  << 20));  // 8-16     (aliased by Kb later)
    bf16_t* Wkt = (bf16_t*)(ws + ((size_t)16 << 20));  // 16-24    (aliased by Ob later)
    bf16_t* Wvt = (bf16_t*)(ws + ((size_t)24 << 20));
    bf16_t* Wot = (bf16_t*)(ws + ((size_t)32 << 20));
    float*  Qf  = (float*) (ws + ((size_t)40 << 20));
    float*  Kf  = (float*) (ws + ((size_t)56 << 20));
    bf16_t* Vt  = (bf16_t*)(ws + ((size_t)72 << 20));  // per-head transposed V
    bf16_t* Qb  = (bf16_t*)(ws);
    bf16_t* Kb  = (bf16_t*)(ws + ((size_t)8  << 20));
    bf16_t* Ob  = (bf16_t*)(ws + ((size_t)16 << 20));

    const int n = S_LEN * D_DIM;

    k_cvt_bf16<<<n / (256 * 8), 256, 0, stream>>>(hs, Xb, n);
    k_transpose4<<<dim3(32, 32, 4), 256, 0, stream>>>(Wq, Wk, Wv, Wo, Wqt, Wkt, Wvt, Wot);

    // QKV projection: Q,K f32; V -> bf16 per-head transposed Vt
    k_gemm_bt<<<dim3(D_DIM / BN, S_LEN / BM, 3), 256, 0, stream>>>(
        Xb, Wqt, Wkt, Wvt, bq, bk, bv, Qf, Kf, Vt, S_LEN, D_DIM, D_DIM);

    // RMSNorm + RoPE -> bf16
    k_norm_rope<<<dim3(S_LEN, 1, 2), 256, 0, stream>>>(Qf, Kf, Qb, Kb, qw, kw, cosb, sinb);

    // MFMA flash attention -> bf16 activations
    k_flash<<<dim3(S_LEN / 128, NHEADS), 256, 0, stream>>>(Qb, Kb, Vt, Ob);

    // output projection
    k_gemm_bt<<<dim3(D_DIM / BN, S_LEN / BM, 1), 256, 0, stream>>>(
        Ob, Wot, Wot, Wot, bo, bo, bo, out, out, (bf16_t*)nullptr, S_LEN, D_DIM, D_DIM);
}

// Round 4
// 357.746 us; speedup vs baseline: 6.2444x; 1.0364x over previous
//
#include <hip/hip_runtime.h>
#include <hip/hip_bf16.h>

typedef __bf16 bf16_t;
typedef __bf16 bf16x8 __attribute__((ext_vector_type(8)));
typedef __bf16 bf16x4 __attribute__((ext_vector_type(4)));
typedef float floatx4 __attribute__((ext_vector_type(4)));
typedef float floatx16 __attribute__((ext_vector_type(16)));

#define S_LEN 2048
#define D_DIM 2048
#define NHEADS 32
#define DH 64

// async global->LDS, 16B per lane; LDS dest = wave-uniform base + lane*16
__device__ __forceinline__ void gll16(const bf16_t* g, bf16_t* l) {
    __builtin_amdgcn_global_load_lds(
        (const __attribute__((address_space(1))) unsigned int*)g,
        (__attribute__((address_space(3))) unsigned int*)l, 16, 0, 0);
}

#define BAR()    asm volatile("s_barrier" ::: "memory")
#define WAIT(N)  asm volatile("s_waitcnt vmcnt(" #N ")" ::: "memory")

// ---------------- f32 -> bf16 elementwise convert ----------------
__global__ __launch_bounds__(256) void k_cvt_bf16(const float* __restrict__ x,
                                                  bf16_t* __restrict__ y, int n) {
    int i = (blockIdx.x * 256 + threadIdx.x) * 8;
    if (i + 8 > n) return;
    const float4 a = *(const float4*)(x + i);
    const float4 b = *(const float4*)(x + i + 4);
    bf16x8 o;
    o[0] = (bf16_t)a.x; o[1] = (bf16_t)a.y; o[2] = (bf16_t)a.z; o[3] = (bf16_t)a.w;
    o[4] = (bf16_t)b.x; o[5] = (bf16_t)b.y; o[6] = (bf16_t)b.z; o[7] = (bf16_t)b.w;
    *(bf16x8*)(y + i) = o;
}

// ---------------- 4x weight transpose W[k][n] f32 -> Wt[n][k] bf16 ----------------
__global__ __launch_bounds__(256) void k_transpose4(
    const float* __restrict__ W0, const float* __restrict__ W1,
    const float* __restrict__ W2, const float* __restrict__ W3,
    bf16_t* __restrict__ T0, bf16_t* __restrict__ T1,
    bf16_t* __restrict__ T2, bf16_t* __restrict__ T3)
{
    const float* W; bf16_t* T;
    switch (blockIdx.z) {
        case 0: W = W0; T = T0; break;
        case 1: W = W1; T = T1; break;
        case 2: W = W2; T = T2; break;
        default: W = W3; T = T3; break;
    }
    __shared__ float tile[64][65];
    const int n0 = blockIdx.x * 64, k0 = blockIdx.y * 64;
    const int tx = threadIdx.x & 63, ty = threadIdx.x >> 6;
    #pragma unroll
    for (int i = 0; i < 16; ++i) {
        int r = i * 4 + ty;
        tile[r][tx] = W[(size_t)(k0 + r) * D_DIM + n0 + tx];
    }
    __syncthreads();
    #pragma unroll
    for (int i = 0; i < 16; ++i) {
        int r = i * 4 + ty;
        T[(size_t)(n0 + r) * D_DIM + k0 + tx] = (bf16_t)tile[tx][r];
    }
}

// ================= GEMM common pieces =================
#define BM 128
#define BN 128
#define BK 32

// QKV GEMM: 2-deep async pipeline, triple-buffered LDS, raw barriers.
// z==0/1: f32 output C0/C1 (+bias). z==2: bf16 transposed output Vt[n][m] (+bias).
__global__ __launch_bounds__(256) void k_gemm_qkv(
    const bf16_t* __restrict__ A,
    const bf16_t* __restrict__ Bt0, const bf16_t* __restrict__ Bt1, const bf16_t* __restrict__ Bt2,
    const float* __restrict__ bias0, const float* __restrict__ bias1, const float* __restrict__ bias2,
    float* __restrict__ C0, float* __restrict__ C1, bf16_t* __restrict__ VtOut,
    int M, int N, int K)
{
    const bf16_t* Bt; const float* bias;
    if (blockIdx.z == 0)      { Bt = Bt0; bias = bias0; }
    else if (blockIdx.z == 1) { Bt = Bt1; bias = bias1; }
    else                      { Bt = Bt2; bias = bias2; }

    __shared__ bf16_t As[3][BM][BK];   // 3 x 8 KB
    __shared__ bf16_t Bs[3][BN][BK];   // 3 x 8 KB

    const int t    = threadIdx.x;
    const int lane = t & 63;
    const int wave = t >> 6;
    const int wm = (wave >> 1) * 64;
    const int wn = (wave & 1) * 64;
    const int bm = blockIdx.y * BM;
    const int bn = blockIdx.x * BN;
    const int lm = lane & 15;
    const int lq = lane >> 4;

    const int srow0 = wave * 32 + (lane >> 2);
    const int srow1 = srow0 + 16;
    const int cp    = lane & 3;
    const int gc0 = cp ^ ((srow0 >> 1) & 3);
    const int gc1 = cp ^ ((srow1 >> 1) & 3);

    const bf16_t* Ag0 = A  + (size_t)(bm + srow0) * K + gc0 * 8;
    const bf16_t* Ag1 = A  + (size_t)(bm + srow1) * K + gc1 * 8;
    const bf16_t* Bg0 = Bt + (size_t)(bn + srow0) * K + gc0 * 8;
    const bf16_t* Bg1 = Bt + (size_t)(bn + srow1) * K + gc1 * 8;

    floatx4 acc[4][4];
    #pragma unroll
    for (int i = 0; i < 4; ++i)
        #pragma unroll
        for (int j = 0; j < 4; ++j)
            #pragma unroll
            for (int r = 0; r < 4; ++r) acc[i][j][r] = 0.f;

    const int NIT = K / BK;
    auto stage = [&](int buf, int k0) {
        gll16(Ag0 + k0, &As[buf][wave * 32][0]);
        gll16(Ag1 + k0, &As[buf][wave * 32 + 16][0]);
        gll16(Bg0 + k0, &Bs[buf][wave * 32][0]);
        gll16(Bg1 + k0, &Bs[buf][wave * 32 + 16][0]);
    };
    stage(0, 0);
    stage(1, BK);

    for (int i = 0; i < NIT; ++i) {
        BAR();                               // all waves done reading buf (i+2)%3's old data
        if (i + 2 < NIT) {
            stage((i + 2) % 3, (i + 2) * BK);
            WAIT(8);                         // set i (oldest) has landed
        } else if (i + 1 < NIT) {
            WAIT(4);
        } else {
            WAIT(0);
        }
        BAR();                               // everyone's set-i data visible

        const int buf = i % 3;
        bf16x8 af[4], bfr[4];
        #pragma unroll
        for (int ii = 0; ii < 4; ++ii) {
            const int row = wm + ii * 16 + lm;
            af[ii] = *(const bf16x8*)&As[buf][row][(lq ^ ((row >> 1) & 3)) * 8];
        }
        #pragma unroll
        for (int j = 0; j < 4; ++j) {
            const int row = wn + j * 16 + lm;
            bfr[j] = *(const bf16x8*)&Bs[buf][row][(lq ^ ((row >> 1) & 3)) * 8];
        }
        #pragma unroll
        for (int ii = 0; ii < 4; ++ii)
            #pragma unroll
            for (int j = 0; j < 4; ++j)
                acc[ii][j] = __builtin_amdgcn_mfma_f32_16x16x32_bf16(af[ii], bfr[j], acc[ii][j], 0, 0, 0);
    }

    if (blockIdx.z == 2) {
        #pragma unroll
        for (int i = 0; i < 4; ++i) {
            const int row0 = bm + wm + i * 16 + lq * 4;
            #pragma unroll
            for (int j = 0; j < 4; ++j) {
                const int col = bn + wn + j * 16 + lm;
                const float bb = bias[col];
                bf16x4 pk;
                #pragma unroll
                for (int r = 0; r < 4; ++r) pk[r] = (bf16_t)(acc[i][j][r] + bb);
                *(bf16x4*)(VtOut + (size_t)col * M + row0) = pk;
            }
        }
    } else {
        float* C = (blockIdx.z == 0) ? C0 : C1;
        #pragma unroll
        for (int i = 0; i < 4; ++i) {
            const int row0 = bm + wm + i * 16 + lq * 4;
            #pragma unroll
            for (int j = 0; j < 4; ++j) {
                const int col = bn + wn + j * 16 + lm;
                const float bb = bias[col];
                #pragma unroll
                for (int r = 0; r < 4; ++r)
                    C[(size_t)(row0 + r) * N + col] = acc[i][j][r] + bb;
            }
        }
    }
}

// Split-K GEMM (O-projection): z in {0,1,2} covers a K-slice, writes f32 partials.
__global__ __launch_bounds__(256) void k_gemm_splitk(
    const bf16_t* __restrict__ A, const bf16_t* __restrict__ Bt,
    float* __restrict__ Cpart, int M, int N, int K)
{
    __shared__ bf16_t As[3][BM][BK];
    __shared__ bf16_t Bs[3][BN][BK];

    const int t    = threadIdx.x;
    const int lane = t & 63;
    const int wave = t >> 6;
    const int wm = (wave >> 1) * 64;
    const int wn = (wave & 1) * 64;
    const int bm = blockIdx.y * BM;
    const int bn = blockIdx.x * BN;
    const int lm = lane & 15;
    const int lq = lane >> 4;
    const int z  = blockIdx.z;

    const int nit_all = K / BK;
    const int it0 = (z * nit_all) / 3;
    const int it1 = ((z + 1) * nit_all) / 3;
    const int NIT = it1 - it0;
    const int kbase = it0 * BK;

    const int srow0 = wave * 32 + (lane >> 2);
    const int srow1 = srow0 + 16;
    const int cp    = lane & 3;
    const int gc0 = cp ^ ((srow0 >> 1) & 3);
    const int gc1 = cp ^ ((srow1 >> 1) & 3);

    const bf16_t* Ag0 = A  + (size_t)(bm + srow0) * K + kbase + gc0 * 8;
    const bf16_t* Ag1 = A  + (size_t)(bm + srow1) * K + kbase + gc1 * 8;
    const bf16_t* Bg0 = Bt + (size_t)(bn + srow0) * K + kbase + gc0 * 8;
    const bf16_t* Bg1 = Bt + (size_t)(bn + srow1) * K + kbase + gc1 * 8;

    floatx4 acc[4][4];
    #pragma unroll
    for (int i = 0; i < 4; ++i)
        #pragma unroll
        for (int j = 0; j < 4; ++j)
            #pragma unroll
            for (int r = 0; r < 4; ++r) acc[i][j][r] = 0.f;

    auto stage = [&](int buf, int k0) {
        gll16(Ag0 + k0, &As[buf][wave * 32][0]);
        gll16(Ag1 + k0, &As[buf][wave * 32 + 16][0]);
        gll16(Bg0 + k0, &Bs[buf][wave * 32][0]);
        gll16(Bg1 + k0, &Bs[buf][wave * 32 + 16][0]);
    };
    stage(0, 0);
    if (1 < NIT) stage(1, BK);

    for (int i = 0; i < NIT; ++i) {
        BAR();
        if (i + 2 < NIT) {
            stage((i + 2) % 3, (i + 2) * BK);
            WAIT(8);
        } else if (i + 1 < NIT) {
            WAIT(4);
        } else {
            WAIT(0);
        }
        BAR();

        const int buf = i % 3;
        bf16x8 af[4], bfr[4];
        #pragma unroll
        for (int ii = 0; ii < 4; ++ii) {
            const int row = wm + ii * 16 + lm;
            af[ii] = *(const bf16x8*)&As[buf][row][(lq ^ ((row >> 1) & 3)) * 8];
        }
        #pragma unroll
        for (int j = 0; j < 4; ++j) {
            const int row = wn + j * 16 + lm;
            bfr[j] = *(const bf16x8*)&Bs[buf][row][(lq ^ ((row >> 1) & 3)) * 8];
        }
        #pragma unroll
        for (int ii = 0; ii < 4; ++ii)
            #pragma unroll
            for (int j = 0; j < 4; ++j)
                acc[ii][j] = __builtin_amdgcn_mfma_f32_16x16x32_bf16(af[ii], bfr[j], acc[ii][j], 0, 0, 0);
    }

    float* C = Cpart + (size_t)z * M * N;
    #pragma unroll
    for (int i = 0; i < 4; ++i) {
        const int row0 = bm + wm + i * 16 + lq * 4;
        #pragma unroll
        for (int j = 0; j < 4; ++j) {
            const int col = bn + wn + j * 16 + lm;
            #pragma unroll
            for (int r = 0; r < 4; ++r)
                C[(size_t)(row0 + r) * N + col] = acc[i][j][r];
        }
    }
}

// out = bias + p0 + p1 + p2
__global__ __launch_bounds__(256) void k_reduce_bias(
    const float* __restrict__ P, const float* __restrict__ bias,
    float* __restrict__ out)
{
    const int i = (blockIdx.x * 256 + threadIdx.x) * 4;
    const size_t NN = (size_t)S_LEN * D_DIM;
    const float4 b  = *(const float4*)(bias + (i & (D_DIM - 1)));
    const float4 a0 = *(const float4*)(P + i);
    const float4 a1 = *(const float4*)(P + NN + i);
    const float4 a2 = *(const float4*)(P + 2 * NN + i);
    float4 o;
    o.x = b.x + a0.x + a1.x + a2.x;
    o.y = b.y + a0.y + a1.y + a2.y;
    o.z = b.z + a0.z + a1.z + a2.z;
    o.w = b.w + a0.w + a1.w + a2.w;
    *(float4*)(out + i) = o;
}

// ---------------- RMSNorm (full D) + interleaved RoPE -> bf16 ----------------
__global__ __launch_bounds__(256) void k_norm_rope(
    const float* __restrict__ Qf, const float* __restrict__ Kf,
    bf16_t* __restrict__ Qb, bf16_t* __restrict__ Kb,
    const float* __restrict__ qw, const float* __restrict__ kw,
    const float* __restrict__ cosb, const float* __restrict__ sinb)
{
    const float* X = (blockIdx.z == 0) ? Qf : Kf;
    bf16_t* Y = (blockIdx.z == 0) ? Qb : Kb;
    const float* w = (blockIdx.z == 0) ? qw : kw;
    const int row = blockIdx.x;
    const int t = threadIdx.x;
    const size_t base = (size_t)row * D_DIM + t * 8;

    float x[8];
    { float4 a = *(const float4*)(X + base); float4 b = *(const float4*)(X + base + 4);
      x[0]=a.x; x[1]=a.y; x[2]=a.z; x[3]=a.w; x[4]=b.x; x[5]=b.y; x[6]=b.z; x[7]=b.w; }

    float ss = 0.f;
    #pragma unroll
    for (int i = 0; i < 8; ++i) ss += x[i] * x[i];
    #pragma unroll
    for (int off = 32; off; off >>= 1) ss += __shfl_xor(ss, off);
    __shared__ float red[4];
    if ((t & 63) == 0) red[t >> 6] = ss;
    __syncthreads();
    const float tot = red[0] + red[1] + red[2] + red[3];
    const float rms = rsqrtf(tot * (1.0f / D_DIM) + 1e-6f);

    float wv[8], c[8], sn[8];
    { float4 a = *(const float4*)(w + t * 8); float4 b = *(const float4*)(w + t * 8 + 4);
      wv[0]=a.x; wv[1]=a.y; wv[2]=a.z; wv[3]=a.w; wv[4]=b.x; wv[5]=b.y; wv[6]=b.z; wv[7]=b.w; }
    { float4 a = *(const float4*)(cosb + base); float4 b = *(const float4*)(cosb + base + 4);
      c[0]=a.x; c[1]=a.y; c[2]=a.z; c[3]=a.w; c[4]=b.x; c[5]=b.y; c[6]=b.z; c[7]=b.w; }
    { float4 a = *(const float4*)(sinb + base); float4 b = *(const float4*)(sinb + base + 4);
      sn[0]=a.x; sn[1]=a.y; sn[2]=a.z; sn[3]=a.w; sn[4]=b.x; sn[5]=b.y; sn[6]=b.z; sn[7]=b.w; }

    bf16x8 o;
    #pragma unroll
    for (int p = 0; p < 4; ++p) {
        const float e  = x[2*p]     * rms * wv[2*p];
        const float od = x[2*p + 1] * rms * wv[2*p + 1];
        o[2*p]     = (bf16_t)(e * c[2*p]     - od * sn[2*p]);
        o[2*p + 1] = (bf16_t)(od * c[2*p + 1] + e * sn[2*p + 1]);
    }
    *(bf16x8*)(Y + base) = o;
}

// ---------------- MFMA flash attention, double-buffered K/V prefetch ----------------
#define LDPQ 72

__global__ __launch_bounds__(256) void k_flash(
    const bf16_t* __restrict__ Qb, const bf16_t* __restrict__ Kb,
    const bf16_t* __restrict__ Vt, bf16_t* __restrict__ Ob)
{
    const int h = blockIdx.y, hc = h * DH;
    const int t = threadIdx.x;
    const int wave = t >> 6, lane = t & 63;
    const int ln = lane & 31, hf = lane >> 5;
    const int qw = blockIdx.x * 128 + wave * 32;

    __shared__ bf16_t Ks[2][64][64];     // [key][dh], swizzled
    __shared__ bf16_t Vs[2][64][64];     // [d][key],  swizzled
    __shared__ bf16_t Ps[4][32][LDPQ];   // per-wave [q][key]

    bf16x8 bq[4];
    #pragma unroll
    for (int kt = 0; kt < 4; ++kt)
        bq[kt] = *(const bf16x8*)(Qb + (size_t)(qw + ln) * D_DIM + hc + kt * 16 + hf * 8);

    const int r0  = wave * 16 + (lane >> 3);
    const int r1  = r0 + 8;
    const int cp8 = lane & 7;
    const int gcA = cp8 ^ (r0 & 7);
    const int gcB = cp8 ^ (r1 & 7);
    const bf16_t* kg0 = Kb + (size_t)r0 * D_DIM + hc + gcA * 8;
    const bf16_t* kg1 = Kb + (size_t)r1 * D_DIM + hc + gcB * 8;
    const bf16_t* vg0 = Vt + (size_t)(hc + r0) * S_LEN + gcA * 8;
    const bf16_t* vg1 = Vt + (size_t)(hc + r1) * S_LEN + gcB * 8;

    auto stageKV = [&](int buf, int kc) {
        gll16(kg0 + (size_t)kc * D_DIM, &Ks[buf][wave * 16][0]);
        gll16(kg1 + (size_t)kc * D_DIM, &Ks[buf][wave * 16 + 8][0]);
        gll16(vg0 + kc, &Vs[buf][wave * 16][0]);
        gll16(vg1 + kc, &Vs[buf][wave * 16 + 8][0]);
    };

    floatx16 o0, o1, lf;
    #pragma unroll
    for (int r = 0; r < 16; ++r) { o0[r] = 0.f; o1[r] = 0.f; lf[r] = 0.f; }

    bf16x8 ones;
    #pragma unroll
    for (int j = 0; j < 8; ++j) ones[j] = (bf16_t)1.0f;

    const int swz = ln & 7;
    const float c_exp = 0.125f * 1.44269504089f;

    stageKV(0, 0);

    for (int kc = 0; kc < S_LEN; kc += 64) {
        const int cur = (kc >> 6) & 1;
        BAR();                              // all waves done reading buf cur^1's old data
        if (kc + 64 < S_LEN) {
            stageKV(cur ^ 1, kc + 64);
            WAIT(4);                        // cur's 4 loads landed
        } else {
            WAIT(0);
        }
        BAR();                              // everyone's cur data visible

        // S^T = K . Q^T
        floatx16 st0, st1;
        #pragma unroll
        for (int r = 0; r < 16; ++r) { st0[r] = 0.f; st1[r] = 0.f; }
        #pragma unroll
        for (int kt = 0; kt < 4; ++kt) {
            const int ch = 2 * kt + hf;
            const bf16x8 a0 = *(const bf16x8*)&Ks[cur][ln]     [(ch ^ swz) * 8];
            const bf16x8 a1 = *(const bf16x8*)&Ks[cur][32 + ln][(ch ^ swz) * 8];
            st0 = __builtin_amdgcn_mfma_f32_32x32x16_bf16(a0, bq[kt], st0, 0, 0, 0);
            st1 = __builtin_amdgcn_mfma_f32_32x32x16_bf16(a1, bq[kt], st1, 0, 0, 0);
        }

        // P^T: col=q(=ln), row=key -> packed b64 writes into wave-private Ps
        #pragma unroll
        for (int g = 0; g < 4; ++g) {
            bf16x4 p0, p1;
            #pragma unroll
            for (int r4 = 0; r4 < 4; ++r4) {
                p0[r4] = (bf16_t)__builtin_amdgcn_exp2f(st0[4 * g + r4] * c_exp);
                p1[r4] = (bf16_t)__builtin_amdgcn_exp2f(st1[4 * g + r4] * c_exp);
            }
            *(bf16x4*)&Ps[wave][ln][8 * g + 4 * hf]      = p0;
            *(bf16x4*)&Ps[wave][ln][32 + 8 * g + 4 * hf] = p1;
        }
        asm volatile("s_waitcnt lgkmcnt(0)" ::: "memory");

        // O += P V ; l += P * 1
        #pragma unroll
        for (int kt = 0; kt < 4; ++kt) {
            const int ch = 2 * kt + hf;
            const bf16x8 ap  = *(const bf16x8*)&Ps[wave][ln][kt * 16 + hf * 8];
            const bf16x8 bv0 = *(const bf16x8*)&Vs[cur][ln]     [(ch ^ swz) * 8];
            const bf16x8 bv1 = *(const bf16x8*)&Vs[cur][32 + ln][(ch ^ swz) * 8];
            o0 = __builtin_amdgcn_mfma_f32_32x32x16_bf16(ap, bv0, o0, 0, 0, 0);
            o1 = __builtin_amdgcn_mfma_f32_32x32x16_bf16(ap, bv1, o1, 0, 0, 0);
            lf = __builtin_amdgcn_mfma_f32_32x32x16_bf16(ap, ones, lf, 0, 0, 0);
        }
    }

    #pragma unroll
    for (int r = 0; r < 16; ++r) {
        const int row = (r & 3) + 8 * (r >> 2) + 4 * hf;
        const float inv = 1.0f / lf[r];
        Ob[(size_t)(qw + row) * D_DIM + hc + ln]      = (bf16_t)(o0[r] * inv);
        Ob[(size_t)(qw + row) * D_DIM + hc + 32 + ln] = (bf16_t)(o1[r] * inv);
    }
}

// ---------------- launcher ----------------
extern "C" void kernel_launch(void* const* d_in, const int* in_sizes, int n_in,
                              void* d_out, int out_size, void* d_ws, size_t ws_size,
                              hipStream_t stream) {
    const float* hs   = (const float*)d_in[0];
    const float* cosb = (const float*)d_in[1];
    const float* sinb = (const float*)d_in[2];
    const float* Wq   = (const float*)d_in[3];
    const float* bq   = (const float*)d_in[4];
    const float* Wk   = (const float*)d_in[5];
    const float* bk   = (const float*)d_in[6];
    const float* Wv   = (const float*)d_in[7];
    const float* bv   = (const float*)d_in[8];
    const float* qw   = (const float*)d_in[9];
    const float* kw   = (const float*)d_in[10];
    const float* Wo   = (const float*)d_in[11];
    const float* bo   = (const float*)d_in[12];
    float* out = (float*)d_out;

    char* ws = (char*)d_ws;
    bf16_t* Xb  = (bf16_t*)(ws);                       // 0-8 MB   (aliased by Qb later)
    bf16_t* Wqt = (bf16_t*)(ws + ((size_t)8  << 20));  // 8-16     (aliased by Kb later)
    bf16_t* Wkt = (bf16_t*)(ws + ((size_t)16 << 20));  // 16-24    (aliased by Ob later)
    bf16_t* Wvt = (bf16_t*)(ws + ((size_t)24 << 20));
    bf16_t* Wot = (bf16_t*)(ws + ((size_t)32 << 20));
    float*  Qf  = (float*) (ws + ((size_t)40 << 20));  // dead after norm_rope
    float*  Kf  = (float*) (ws + ((size_t)56 << 20));  // dead after norm_rope
    bf16_t* Vt  = (bf16_t*)(ws + ((size_t)72 << 20));  // dead after flash
    bf16_t* Qb  = (bf16_t*)(ws);
    bf16_t* Kb  = (bf16_t*)(ws + ((size_t)8  << 20));
    bf16_t* Ob  = (bf16_t*)(ws + ((size_t)16 << 20));
    float*  Pp  = (float*) (ws + ((size_t)40 << 20));  // 3x16 MB partials (40-88 MB)

    const int n = S_LEN * D_DIM;

    k_cvt_bf16<<<n / (256 * 8), 256, 0, stream>>>(hs, Xb, n);
    k_transpose4<<<dim3(32, 32, 4), 256, 0, stream>>>(Wq, Wk, Wv, Wo, Wqt, Wkt, Wvt, Wot);

    // QKV projection: Q,K f32; V -> bf16 per-head transposed Vt
    k_gemm_qkv<<<dim3(D_DIM / BN, S_LEN / BM, 3), 256, 0, stream>>>(
        Xb, Wqt, Wkt, Wvt, bq, bk, bv, Qf, Kf, Vt, S_LEN, D_DIM, D_DIM);

    // RMSNorm + RoPE -> bf16
    k_norm_rope<<<dim3(S_LEN, 1, 2), 256, 0, stream>>>(Qf, Kf, Qb, Kb, qw, kw, cosb, sinb);

    // MFMA flash attention -> bf16 activations
    k_flash<<<dim3(S_LEN / 128, NHEADS), 256, 0, stream>>>(Qb, Kb, Vt, Ob);

    // output projection: split-K=3 partials + reduce(+bias)
    k_gemm_splitk<<<dim3(D_DIM / BN, S_LEN / BM, 3), 256, 0, stream>>>(
        Ob, Wot, Pp, S_LEN, D_DIM, D_DIM);
    k_reduce_bias<<<n / (256 * 4), 256, 0, stream>>>(Pp, bo, out);
}

// Round 5
// 321.490 us; speedup vs baseline: 6.9487x; 1.1128x over previous
//
#include <hip/hip_runtime.h>
#include <hip/hip_bf16.h>

typedef __bf16 bf16_t;
typedef __bf16 bf16x8 __attribute__((ext_vector_type(8)));
typedef __bf16 bf16x4 __attribute__((ext_vector_type(4)));
typedef float floatx4 __attribute__((ext_vector_type(4)));
typedef float floatx16 __attribute__((ext_vector_type(16)));

#define S_LEN 2048
#define D_DIM 2048
#define NHEADS 32
#define DH 64

// async global->LDS, 16B per lane; LDS dest = wave-uniform base + lane*16
__device__ __forceinline__ void gll16(const bf16_t* g, bf16_t* l) {
    __builtin_amdgcn_global_load_lds(
        (const __attribute__((address_space(1))) unsigned int*)g,
        (__attribute__((address_space(3))) unsigned int*)l, 16, 0, 0);
}

#define BAR()    asm volatile("s_barrier" ::: "memory")
#define WAIT(N)  asm volatile("s_waitcnt vmcnt(" #N ")" ::: "memory")
#define DSWAIT() asm volatile("s_waitcnt lgkmcnt(0)" ::: "memory")

// ---------------- f32 -> bf16 elementwise convert ----------------
__global__ __launch_bounds__(256) void k_cvt_bf16(const float* __restrict__ x,
                                                  bf16_t* __restrict__ y, int n) {
    int i = (blockIdx.x * 256 + threadIdx.x) * 8;
    if (i + 8 > n) return;
    const float4 a = *(const float4*)(x + i);
    const float4 b = *(const float4*)(x + i + 4);
    bf16x8 o;
    o[0] = (bf16_t)a.x; o[1] = (bf16_t)a.y; o[2] = (bf16_t)a.z; o[3] = (bf16_t)a.w;
    o[4] = (bf16_t)b.x; o[5] = (bf16_t)b.y; o[6] = (bf16_t)b.z; o[7] = (bf16_t)b.w;
    *(bf16x8*)(y + i) = o;
}

// ---------------- 4x weight transpose W[k][n] f32 -> Wt[n][k] bf16 ----------------
__global__ __launch_bounds__(256) void k_transpose4(
    const float* __restrict__ W0, const float* __restrict__ W1,
    const float* __restrict__ W2, const float* __restrict__ W3,
    bf16_t* __restrict__ T0, bf16_t* __restrict__ T1,
    bf16_t* __restrict__ T2, bf16_t* __restrict__ T3)
{
    const float* W; bf16_t* T;
    switch (blockIdx.z) {
        case 0: W = W0; T = T0; break;
        case 1: W = W1; T = T1; break;
        case 2: W = W2; T = T2; break;
        default: W = W3; T = T3; break;
    }
    __shared__ float tile[64][65];
    const int n0 = blockIdx.x * 64, k0 = blockIdx.y * 64;
    const int tx = threadIdx.x & 63, ty = threadIdx.x >> 6;
    #pragma unroll
    for (int i = 0; i < 16; ++i) {
        int r = i * 4 + ty;
        tile[r][tx] = W[(size_t)(k0 + r) * D_DIM + n0 + tx];
    }
    __syncthreads();
    #pragma unroll
    for (int i = 0; i < 16; ++i) {
        int r = i * 4 + ty;
        T[(size_t)(n0 + r) * D_DIM + k0 + tx] = (bf16_t)tile[tx][r];
    }
}

// ================= GEMM =================
#define BM 128
#define BN 128
#define BK 32

// QKV GEMM: 2-deep async pipeline, triple-buffered LDS, raw barriers.
// z==0/1: bf16 row-major Q/K (+bias). z==2: bf16 transposed Vt[n][m] (+bias).
__global__ __launch_bounds__(256) void k_gemm_qkv(
    const bf16_t* __restrict__ A,
    const bf16_t* __restrict__ Bt0, const bf16_t* __restrict__ Bt1, const bf16_t* __restrict__ Bt2,
    const float* __restrict__ bias0, const float* __restrict__ bias1, const float* __restrict__ bias2,
    bf16_t* __restrict__ Qout, bf16_t* __restrict__ Kout, bf16_t* __restrict__ VtOut,
    int M, int N, int K)
{
    const bf16_t* Bt; const float* bias;
    if (blockIdx.z == 0)      { Bt = Bt0; bias = bias0; }
    else if (blockIdx.z == 1) { Bt = Bt1; bias = bias1; }
    else                      { Bt = Bt2; bias = bias2; }

    __shared__ bf16_t As[3][BM][BK];
    __shared__ bf16_t Bs[3][BN][BK];

    const int t    = threadIdx.x;
    const int lane = t & 63;
    const int wave = t >> 6;
    const int wm = (wave >> 1) * 64;
    const int wn = (wave & 1) * 64;
    const int bm = blockIdx.y * BM;
    const int bn = blockIdx.x * BN;
    const int lm = lane & 15;
    const int lq = lane >> 4;

    const int srow0 = wave * 32 + (lane >> 2);
    const int srow1 = srow0 + 16;
    const int cp    = lane & 3;
    const int gc0 = cp ^ ((srow0 >> 1) & 3);
    const int gc1 = cp ^ ((srow1 >> 1) & 3);

    const bf16_t* Ag0 = A  + (size_t)(bm + srow0) * K + gc0 * 8;
    const bf16_t* Ag1 = A  + (size_t)(bm + srow1) * K + gc1 * 8;
    const bf16_t* Bg0 = Bt + (size_t)(bn + srow0) * K + gc0 * 8;
    const bf16_t* Bg1 = Bt + (size_t)(bn + srow1) * K + gc1 * 8;

    floatx4 acc[4][4];
    #pragma unroll
    for (int i = 0; i < 4; ++i)
        #pragma unroll
        for (int j = 0; j < 4; ++j)
            #pragma unroll
            for (int r = 0; r < 4; ++r) acc[i][j][r] = 0.f;

    const int NIT = K / BK;
    auto stage = [&](int buf, int k0) {
        gll16(Ag0 + k0, &As[buf][wave * 32][0]);
        gll16(Ag1 + k0, &As[buf][wave * 32 + 16][0]);
        gll16(Bg0 + k0, &Bs[buf][wave * 32][0]);
        gll16(Bg1 + k0, &Bs[buf][wave * 32 + 16][0]);
    };
    stage(0, 0);
    stage(1, BK);

    for (int i = 0; i < NIT; ++i) {
        BAR();
        if (i + 2 < NIT) {
            stage((i + 2) % 3, (i + 2) * BK);
            WAIT(8);
        } else if (i + 1 < NIT) {
            WAIT(4);
        } else {
            WAIT(0);
        }
        BAR();

        const int buf = i % 3;
        bf16x8 af[4], bfr[4];
        #pragma unroll
        for (int ii = 0; ii < 4; ++ii) {
            const int row = wm + ii * 16 + lm;
            af[ii] = *(const bf16x8*)&As[buf][row][(lq ^ ((row >> 1) & 3)) * 8];
        }
        #pragma unroll
        for (int j = 0; j < 4; ++j) {
            const int row = wn + j * 16 + lm;
            bfr[j] = *(const bf16x8*)&Bs[buf][row][(lq ^ ((row >> 1) & 3)) * 8];
        }
        #pragma unroll
        for (int ii = 0; ii < 4; ++ii)
            #pragma unroll
            for (int j = 0; j < 4; ++j)
                acc[ii][j] = __builtin_amdgcn_mfma_f32_16x16x32_bf16(af[ii], bfr[j], acc[ii][j], 0, 0, 0);
    }

    if (blockIdx.z == 2) {
        #pragma unroll
        for (int i = 0; i < 4; ++i) {
            const int row0 = bm + wm + i * 16 + lq * 4;
            #pragma unroll
            for (int j = 0; j < 4; ++j) {
                const int col = bn + wn + j * 16 + lm;
                const float bb = bias[col];
                bf16x4 pk;
                #pragma unroll
                for (int r = 0; r < 4; ++r) pk[r] = (bf16_t)(acc[i][j][r] + bb);
                *(bf16x4*)(VtOut + (size_t)col * M + row0) = pk;
            }
        }
    } else {
        bf16_t* C = (blockIdx.z == 0) ? Qout : Kout;
        #pragma unroll
        for (int i = 0; i < 4; ++i) {
            const int row0 = bm + wm + i * 16 + lq * 4;
            #pragma unroll
            for (int j = 0; j < 4; ++j) {
                const int col = bn + wn + j * 16 + lm;
                const float bb = bias[col];
                #pragma unroll
                for (int r = 0; r < 4; ++r)
                    C[(size_t)(row0 + r) * N + col] = (bf16_t)(acc[i][j][r] + bb);
            }
        }
    }
}

// Split-K GEMM (O-projection): z in {0,1,2} covers a K-slice, writes f32 partials.
__global__ __launch_bounds__(256) void k_gemm_splitk(
    const bf16_t* __restrict__ A, const bf16_t* __restrict__ Bt,
    float* __restrict__ P0, float* __restrict__ P1, float* __restrict__ P2,
    int M, int N, int K)
{
    __shared__ bf16_t As[3][BM][BK];
    __shared__ bf16_t Bs[3][BN][BK];

    const int t    = threadIdx.x;
    const int lane = t & 63;
    const int wave = t >> 6;
    const int wm = (wave >> 1) * 64;
    const int wn = (wave & 1) * 64;
    const int bm = blockIdx.y * BM;
    const int bn = blockIdx.x * BN;
    const int lm = lane & 15;
    const int lq = lane >> 4;
    const int z  = blockIdx.z;

    const int nit_all = K / BK;
    const int it0 = (z * nit_all) / 3;
    const int it1 = ((z + 1) * nit_all) / 3;
    const int NIT = it1 - it0;
    const int kbase = it0 * BK;

    const int srow0 = wave * 32 + (lane >> 2);
    const int srow1 = srow0 + 16;
    const int cp    = lane & 3;
    const int gc0 = cp ^ ((srow0 >> 1) & 3);
    const int gc1 = cp ^ ((srow1 >> 1) & 3);

    const bf16_t* Ag0 = A  + (size_t)(bm + srow0) * K + kbase + gc0 * 8;
    const bf16_t* Ag1 = A  + (size_t)(bm + srow1) * K + kbase + gc1 * 8;
    const bf16_t* Bg0 = Bt + (size_t)(bn + srow0) * K + kbase + gc0 * 8;
    const bf16_t* Bg1 = Bt + (size_t)(bn + srow1) * K + kbase + gc1 * 8;

    floatx4 acc[4][4];
    #pragma unroll
    for (int i = 0; i < 4; ++i)
        #pragma unroll
        for (int j = 0; j < 4; ++j)
            #pragma unroll
            for (int r = 0; r < 4; ++r) acc[i][j][r] = 0.f;

    auto stage = [&](int buf, int k0) {
        gll16(Ag0 + k0, &As[buf][wave * 32][0]);
        gll16(Ag1 + k0, &As[buf][wave * 32 + 16][0]);
        gll16(Bg0 + k0, &Bs[buf][wave * 32][0]);
        gll16(Bg1 + k0, &Bs[buf][wave * 32 + 16][0]);
    };
    stage(0, 0);
    if (1 < NIT) stage(1, BK);

    for (int i = 0; i < NIT; ++i) {
        BAR();
        if (i + 2 < NIT) {
            stage((i + 2) % 3, (i + 2) * BK);
            WAIT(8);
        } else if (i + 1 < NIT) {
            WAIT(4);
        } else {
            WAIT(0);
        }
        BAR();

        const int buf = i % 3;
        bf16x8 af[4], bfr[4];
        #pragma unroll
        for (int ii = 0; ii < 4; ++ii) {
            const int row = wm + ii * 16 + lm;
            af[ii] = *(const bf16x8*)&As[buf][row][(lq ^ ((row >> 1) & 3)) * 8];
        }
        #pragma unroll
        for (int j = 0; j < 4; ++j) {
            const int row = wn + j * 16 + lm;
            bfr[j] = *(const bf16x8*)&Bs[buf][row][(lq ^ ((row >> 1) & 3)) * 8];
        }
        #pragma unroll
        for (int ii = 0; ii < 4; ++ii)
            #pragma unroll
            for (int j = 0; j < 4; ++j)
                acc[ii][j] = __builtin_amdgcn_mfma_f32_16x16x32_bf16(af[ii], bfr[j], acc[ii][j], 0, 0, 0);
    }

    float* C = (z == 0) ? P0 : (z == 1) ? P1 : P2;
    #pragma unroll
    for (int i = 0; i < 4; ++i) {
        const int row0 = bm + wm + i * 16 + lq * 4;
        #pragma unroll
        for (int j = 0; j < 4; ++j) {
            const int col = bn + wn + j * 16 + lm;
            #pragma unroll
            for (int r = 0; r < 4; ++r)
                C[(size_t)(row0 + r) * N + col] = acc[i][j][r];
        }
    }
}

// out = bias + p0 + p1 + p2
__global__ __launch_bounds__(256) void k_reduce_bias(
    const float* __restrict__ P0, const float* __restrict__ P1,
    const float* __restrict__ P2, const float* __restrict__ bias,
    float* __restrict__ out)
{
    const int i = (blockIdx.x * 256 + threadIdx.x) * 4;
    const float4 b  = *(const float4*)(bias + (i & (D_DIM - 1)));
    const float4 a0 = *(const float4*)(P0 + i);
    const float4 a1 = *(const float4*)(P1 + i);
    const float4 a2 = *(const float4*)(P2 + i);
    float4 o;
    o.x = b.x + a0.x + a1.x + a2.x;
    o.y = b.y + a0.y + a1.y + a2.y;
    o.z = b.z + a0.z + a1.z + a2.z;
    o.w = b.w + a0.w + a1.w + a2.w;
    *(float4*)(out + i) = o;
}

// ---------------- RMSNorm (full D) + interleaved RoPE, bf16 in-place ----------------
// cos/sin tables have period 64 in the column dim -> read only 64 cols per row.
__global__ __launch_bounds__(256) void k_norm_rope(
    bf16_t* __restrict__ Q, bf16_t* __restrict__ Kb_,
    const float* __restrict__ qw, const float* __restrict__ kw,
    const float* __restrict__ cosb, const float* __restrict__ sinb)
{
    bf16_t* X = (blockIdx.z == 0) ? Q : Kb_;
    const float* w = (blockIdx.z == 0) ? qw : kw;
    const int row = blockIdx.x;
    const int t = threadIdx.x;
    const size_t base = (size_t)row * D_DIM + t * 8;

    const bf16x8 xv = *(const bf16x8*)(X + base);
    float x[8];
    #pragma unroll
    for (int i = 0; i < 8; ++i) x[i] = (float)xv[i];

    float ss = 0.f;
    #pragma unroll
    for (int i = 0; i < 8; ++i) ss += x[i] * x[i];
    #pragma unroll
    for (int off = 32; off; off >>= 1) ss += __shfl_xor(ss, off);
    __shared__ float red[4];
    if ((t & 63) == 0) red[t >> 6] = ss;
    __syncthreads();
    const float tot = red[0] + red[1] + red[2] + red[3];
    const float rms = rsqrtf(tot * (1.0f / D_DIM) + 1e-6f);

    float wv[8], c[8], sn[8];
    { float4 a = *(const float4*)(w + t * 8); float4 b = *(const float4*)(w + t * 8 + 4);
      wv[0]=a.x; wv[1]=a.y; wv[2]=a.z; wv[3]=a.w; wv[4]=b.x; wv[5]=b.y; wv[6]=b.z; wv[7]=b.w; }
    const size_t cbase = (size_t)row * D_DIM + ((t * 8) & 63);
    { float4 a = *(const float4*)(cosb + cbase); float4 b = *(const float4*)(cosb + cbase + 4);
      c[0]=a.x; c[1]=a.y; c[2]=a.z; c[3]=a.w; c[4]=b.x; c[5]=b.y; c[6]=b.z; c[7]=b.w; }
    { float4 a = *(const float4*)(sinb + cbase); float4 b = *(const float4*)(sinb + cbase + 4);
      sn[0]=a.x; sn[1]=a.y; sn[2]=a.z; sn[3]=a.w; sn[4]=b.x; sn[5]=b.y; sn[6]=b.z; sn[7]=b.w; }

    bf16x8 o;
    #pragma unroll
    for (int p = 0; p < 4; ++p) {
        const float e  = x[2*p]     * rms * wv[2*p];
        const float od = x[2*p + 1] * rms * wv[2*p + 1];
        o[2*p]     = (bf16_t)(e * c[2*p]     - od * sn[2*p]);
        o[2*p + 1] = (bf16_t)(od * c[2*p + 1] + e * sn[2*p + 1]);
    }
    *(bf16x8*)(X + base) = o;
}

// ---------------- MFMA flash attention, 3-deep KV prefetch, VALU row-sums ----------------
#define LDPQ 72

__global__ __launch_bounds__(256) void k_flash(
    const bf16_t* __restrict__ Qb, const bf16_t* __restrict__ Kb,
    const bf16_t* __restrict__ Vt, bf16_t* __restrict__ Ob)
{
    // XCD-aware mapping: each XCD (bid&7) handles 4 heads -> 2 MB KV fits its L2
    const int bid = blockIdx.x;
    const int jj  = bid >> 3;
    const int h   = ((bid & 7) << 2) | (jj >> 4);
    const int qblk = jj & 15;
    const int hc = h * DH;
    const int t = threadIdx.x;
    const int wave = t >> 6, lane = t & 63;
    const int ln = lane & 31, hf = lane >> 5;
    const int qw = qblk * 128 + wave * 32;

    __shared__ bf16_t Ks[3][64][64];     // [key][dh], swizzled
    __shared__ bf16_t Vs[3][64][64];     // [d][key],  swizzled
    __shared__ bf16_t Ps[4][32][LDPQ];   // per-wave [q][key]
    __shared__ float  Lw[4][32];         // per-wave l transpose

    bf16x8 bq[4];
    #pragma unroll
    for (int kt = 0; kt < 4; ++kt)
        bq[kt] = *(const bf16x8*)(Qb + (size_t)(qw + ln) * D_DIM + hc + kt * 16 + hf * 8);

    const int r0  = wave * 16 + (lane >> 3);
    const int r1  = r0 + 8;
    const int cp8 = lane & 7;
    const int gcA = cp8 ^ (r0 & 7);
    const int gcB = cp8 ^ (r1 & 7);
    const bf16_t* kg0 = Kb + (size_t)r0 * D_DIM + hc + gcA * 8;
    const bf16_t* kg1 = Kb + (size_t)r1 * D_DIM + hc + gcB * 8;
    const bf16_t* vg0 = Vt + (size_t)(hc + r0) * S_LEN + gcA * 8;
    const bf16_t* vg1 = Vt + (size_t)(hc + r1) * S_LEN + gcB * 8;

    auto stageKV = [&](int buf, int kc) {
        gll16(kg0 + (size_t)kc * D_DIM, &Ks[buf][wave * 16][0]);
        gll16(kg1 + (size_t)kc * D_DIM, &Ks[buf][wave * 16 + 8][0]);
        gll16(vg0 + kc, &Vs[buf][wave * 16][0]);
        gll16(vg1 + kc, &Vs[buf][wave * 16 + 8][0]);
    };

    floatx16 o0, o1;
    #pragma unroll
    for (int r = 0; r < 16; ++r) { o0[r] = 0.f; o1[r] = 0.f; }
    float lsum = 0.f;  // this lane's half-key partial row-sum for q = ln

    const int swz = ln & 7;
    const float c_exp = 0.125f * 1.44269504089f;

    stageKV(0, 0);
    stageKV(1, 64);

    for (int kc = 0; kc < S_LEN; kc += 64) {
        const int cur = (kc >> 6) % 3;
        BAR();                              // all waves done with buf being overwritten
        if (kc + 128 < S_LEN) {
            stageKV((kc / 64 + 2) % 3, kc + 128);
            WAIT(8);                        // chunk kc's 4 loads landed
        } else if (kc + 64 < S_LEN) {
            WAIT(4);
        } else {
            WAIT(0);
        }
        BAR();                              // everyone's chunk-kc data visible

        // S^T = K . Q^T
        floatx16 st0, st1;
        #pragma unroll
        for (int r = 0; r < 16; ++r) { st0[r] = 0.f; st1[r] = 0.f; }
        #pragma unroll
        for (int kt = 0; kt < 4; ++kt) {
            const int ch = 2 * kt + hf;
            const bf16x8 a0 = *(const bf16x8*)&Ks[cur][ln]     [(ch ^ swz) * 8];
            const bf16x8 a1 = *(const bf16x8*)&Ks[cur][32 + ln][(ch ^ swz) * 8];
            st0 = __builtin_amdgcn_mfma_f32_32x32x16_bf16(a0, bq[kt], st0, 0, 0, 0);
            st1 = __builtin_amdgcn_mfma_f32_32x32x16_bf16(a1, bq[kt], st1, 0, 0, 0);
        }

        // P^T: col=q(=ln), row=key -> packed b64 writes; accumulate l on VALU
        #pragma unroll
        for (int g = 0; g < 4; ++g) {
            bf16x4 p0, p1;
            #pragma unroll
            for (int r4 = 0; r4 < 4; ++r4) {
                const float e0 = __builtin_amdgcn_exp2f(st0[4 * g + r4] * c_exp);
                const float e1 = __builtin_amdgcn_exp2f(st1[4 * g + r4] * c_exp);
                p0[r4] = (bf16_t)e0; p1[r4] = (bf16_t)e1;
                lsum += e0 + e1;
            }
            *(bf16x4*)&Ps[wave][ln][8 * g + 4 * hf]      = p0;
            *(bf16x4*)&Ps[wave][ln][32 + 8 * g + 4 * hf] = p1;
        }
        DSWAIT();   // wave-private LDS round-trip

        // O += P V
        #pragma unroll
        for (int kt = 0; kt < 4; ++kt) {
            const int ch = 2 * kt + hf;
            const bf16x8 ap  = *(const bf16x8*)&Ps[wave][ln][kt * 16 + hf * 8];
            const bf16x8 bv0 = *(const bf16x8*)&Vs[cur][ln]     [(ch ^ swz) * 8];
            const bf16x8 bv1 = *(const bf16x8*)&Vs[cur][32 + ln][(ch ^ swz) * 8];
            o0 = __builtin_amdgcn_mfma_f32_32x32x16_bf16(ap, bv0, o0, 0, 0, 0);
            o1 = __builtin_amdgcn_mfma_f32_32x32x16_bf16(ap, bv1, o1, 0, 0, 0);
        }
    }

    // l[q=ln] = own half + partner half; redistribute to C-layout rows via LDS
    const float ltot = lsum + __shfl_xor(lsum, 32);
    if (hf == 0) Lw[wave][ln] = ltot;
    DSWAIT();
    float4 li[4];
    li[0] = *(const float4*)&Lw[wave][4 * hf];
    li[1] = *(const float4*)&Lw[wave][8 + 4 * hf];
    li[2] = *(const float4*)&Lw[wave][16 + 4 * hf];
    li[3] = *(const float4*)&Lw[wave][24 + 4 * hf];

    #pragma unroll
    for (int r = 0; r < 16; ++r) {
        const int row = (r & 3) + 8 * (r >> 2) + 4 * hf;
        const float lv = (r & 3) == 0 ? li[r >> 2].x : (r & 3) == 1 ? li[r >> 2].y
                       : (r & 3) == 2 ? li[r >> 2].z : li[r >> 2].w;
        const float inv = 1.0f / lv;
        Ob[(size_t)(qw + row) * D_DIM + hc + ln]      = (bf16_t)(o0[r] * inv);
        Ob[(size_t)(qw + row) * D_DIM + hc + 32 + ln] = (bf16_t)(o1[r] * inv);
    }
}

// ---------------- launcher ----------------
extern "C" void kernel_launch(void* const* d_in, const int* in_sizes, int n_in,
                              void* d_out, int out_size, void* d_ws, size_t ws_size,
                              hipStream_t stream) {
    const float* hs   = (const float*)d_in[0];
    const float* cosb = (const float*)d_in[1];
    const float* sinb = (const float*)d_in[2];
    const float* Wq   = (const float*)d_in[3];
    const float* bq   = (const float*)d_in[4];
    const float* Wk   = (const float*)d_in[5];
    const float* bk   = (const float*)d_in[6];
    const float* Wv   = (const float*)d_in[7];
    const float* bv   = (const float*)d_in[8];
    const float* qw   = (const float*)d_in[9];
    const float* kw   = (const float*)d_in[10];
    const float* Wo   = (const float*)d_in[11];
    const float* bo   = (const float*)d_in[12];
    float* out = (float*)d_out;

    char* ws = (char*)d_ws;
    // 0-8 Xb | 8-16 Wqt | 16-24 Wkt | 24-32 Wvt   (all dead after QKV GEMM)
    // 32-40 Wot (live until splitk) | 40-48 Qb | 48-56 Kb | 56-64 Vt | 64-72 Ob
    // partials alias dead regions: P0 0-16, P1 16-32, P2 48-64 (Kb/Vt dead after flash)
    bf16_t* Xb  = (bf16_t*)(ws);
    bf16_t* Wqt = (bf16_t*)(ws + ((size_t)8  << 20));
    bf16_t* Wkt = (bf16_t*)(ws + ((size_t)16 << 20));
    bf16_t* Wvt = (bf16_t*)(ws + ((size_t)24 << 20));
    bf16_t* Wot = (bf16_t*)(ws + ((size_t)32 << 20));
    bf16_t* Qb  = (bf16_t*)(ws + ((size_t)40 << 20));
    bf16_t* Kb  = (bf16_t*)(ws + ((size_t)48 << 20));
    bf16_t* Vt  = (bf16_t*)(ws + ((size_t)56 << 20));
    bf16_t* Ob  = (bf16_t*)(ws + ((size_t)64 << 20));
    float*  P0  = (float*) (ws);
    float*  P1  = (float*) (ws + ((size_t)16 << 20));
    float*  P2  = (float*) (ws + ((size_t)48 << 20));

    const int n = S_LEN * D_DIM;

    k_cvt_bf16<<<n / (256 * 8), 256, 0, stream>>>(hs, Xb, n);
    k_transpose4<<<dim3(32, 32, 4), 256, 0, stream>>>(Wq, Wk, Wv, Wo, Wqt, Wkt, Wvt, Wot);

    // QKV projection: Q,K bf16 row-major; V -> bf16 per-head transposed Vt
    k_gemm_qkv<<<dim3(D_DIM / BN, S_LEN / BM, 3), 256, 0, stream>>>(
        Xb, Wqt, Wkt, Wvt, bq, bk, bv, Qb, Kb, Vt, S_LEN, D_DIM, D_DIM);

    // RMSNorm + RoPE, bf16 in-place
    k_norm_rope<<<dim3(S_LEN, 1, 2), 256, 0, stream>>>(Qb, Kb, qw, kw, cosb, sinb);

    // MFMA flash attention -> bf16 activations
    k_flash<<<512, 256, 0, stream>>>(Qb, Kb, Vt, Ob);

    // output projection: split-K=3 partials + reduce(+bias)
    k_gemm_splitk<<<dim3(D_DIM / BN, S_LEN / BM, 3), 256, 0, stream>>>(
        Ob, Wot, P0, P1, P2, S_LEN, D_DIM, D_DIM);
    k_reduce_bias<<<n / (256 * 4), 256, 0, stream>>>(P0, P1, P2, bo, out);
}

// Round 6
// 314.012 us; speedup vs baseline: 7.1141x; 1.0238x over previous
//
#include <hip/hip_runtime.h>
#include <hip/hip_bf16.h>

typedef __bf16 bf16_t;
typedef __bf16 bf16x8 __attribute__((ext_vector_type(8)));
typedef __bf16 bf16x4 __attribute__((ext_vector_type(4)));
typedef float floatx4 __attribute__((ext_vector_type(4)));
typedef float floatx16 __attribute__((ext_vector_type(16)));

#define S_LEN 2048
#define D_DIM 2048
#define NHEADS 32
#define DH 64

// async global->LDS, 16B per lane; LDS dest = wave-uniform base + lane*16
__device__ __forceinline__ void gll16(const bf16_t* g, bf16_t* l) {
    __builtin_amdgcn_global_load_lds(
        (const __attribute__((address_space(1))) unsigned int*)g,
        (__attribute__((address_space(3))) unsigned int*)l, 16, 0, 0);
}

#define BAR()    asm volatile("s_barrier" ::: "memory")
#define WAIT(N)  asm volatile("s_waitcnt vmcnt(" #N ")" ::: "memory")
#define DSWAIT() asm volatile("s_waitcnt lgkmcnt(0)" ::: "memory")

// ---------------- prep: z=0..3 weight transpose+cvt, z=4 hidden-state cvt ----------------
__global__ __launch_bounds__(256) void k_prep(
    const float* __restrict__ hs, bf16_t* __restrict__ Xb,
    const float* __restrict__ W0, const float* __restrict__ W1,
    const float* __restrict__ W2, const float* __restrict__ W3,
    bf16_t* __restrict__ T0, bf16_t* __restrict__ T1,
    bf16_t* __restrict__ T2, bf16_t* __restrict__ T3)
{
    const int t = threadIdx.x;
    if (blockIdx.z == 4) {
        // cvt f32->bf16: 1024 blocks x 4096 elems
        const int bid = blockIdx.y * 32 + blockIdx.x;
        const int i = (bid * 256 + t) * 16;
        const float4 a0 = *(const float4*)(hs + i);
        const float4 a1 = *(const float4*)(hs + i + 4);
        const float4 a2 = *(const float4*)(hs + i + 8);
        const float4 a3 = *(const float4*)(hs + i + 12);
        bf16x8 o0, o1;
        o0[0]=(bf16_t)a0.x; o0[1]=(bf16_t)a0.y; o0[2]=(bf16_t)a0.z; o0[3]=(bf16_t)a0.w;
        o0[4]=(bf16_t)a1.x; o0[5]=(bf16_t)a1.y; o0[6]=(bf16_t)a1.z; o0[7]=(bf16_t)a1.w;
        o1[0]=(bf16_t)a2.x; o1[1]=(bf16_t)a2.y; o1[2]=(bf16_t)a2.z; o1[3]=(bf16_t)a2.w;
        o1[4]=(bf16_t)a3.x; o1[5]=(bf16_t)a3.y; o1[6]=(bf16_t)a3.z; o1[7]=(bf16_t)a3.w;
        *(bf16x8*)(Xb + i) = o0;
        *(bf16x8*)(Xb + i + 8) = o1;
        return;
    }
    const float* W; bf16_t* T;
    switch (blockIdx.z) {
        case 0: W = W0; T = T0; break;
        case 1: W = W1; T = T1; break;
        case 2: W = W2; T = T2; break;
        default: W = W3; T = T3; break;
    }
    __shared__ float tile_t[64][68];   // [n][k], row = 272B (16B-aligned)
    const int n0 = blockIdx.x * 64, k0 = blockIdx.y * 64;
    // load: coalesced f32 rows, LDS transpose-scatter
    #pragma unroll
    for (int i = 0; i < 16; ++i) {
        const int r = i * 4 + (t >> 6);   // k-local, wave-uniform
        const int c = t & 63;             // n-local
        tile_t[c][r] = W[(size_t)(k0 + r) * D_DIM + n0 + c];
    }
    __syncthreads();
    // store: each lane 4 consecutive k as bf16x4 (8B stores)
    #pragma unroll
    for (int j = 0; j < 4; ++j) {
        const int n  = j * 16 + (t >> 4);
        const int k4 = (t & 15) * 4;
        const float4 v = *(const float4*)&tile_t[n][k4];
        bf16x4 pk;
        pk[0] = (bf16_t)v.x; pk[1] = (bf16_t)v.y; pk[2] = (bf16_t)v.z; pk[3] = (bf16_t)v.w;
        *(bf16x4*)(T + (size_t)(n0 + n) * D_DIM + k0 + k4) = pk;
    }
}

// ================= GEMM =================
#define BM 128
#define BN 128
#define BK 32

// QKV GEMM: 2-deep async pipeline, triple-buffered LDS, raw barriers.
__global__ __launch_bounds__(256) void k_gemm_qkv(
    const bf16_t* __restrict__ A,
    const bf16_t* __restrict__ Bt0, const bf16_t* __restrict__ Bt1, const bf16_t* __restrict__ Bt2,
    const float* __restrict__ bias0, const float* __restrict__ bias1, const float* __restrict__ bias2,
    bf16_t* __restrict__ Qout, bf16_t* __restrict__ Kout, bf16_t* __restrict__ VtOut,
    int M, int N, int K)
{
    const bf16_t* Bt; const float* bias;
    if (blockIdx.z == 0)      { Bt = Bt0; bias = bias0; }
    else if (blockIdx.z == 1) { Bt = Bt1; bias = bias1; }
    else                      { Bt = Bt2; bias = bias2; }

    __shared__ bf16_t As[3][BM][BK];
    __shared__ bf16_t Bs[3][BN][BK];

    const int t    = threadIdx.x;
    const int lane = t & 63;
    const int wave = t >> 6;
    const int wm = (wave >> 1) * 64;
    const int wn = (wave & 1) * 64;
    const int bm = blockIdx.y * BM;
    const int bn = blockIdx.x * BN;
    const int lm = lane & 15;
    const int lq = lane >> 4;

    const int srow0 = wave * 32 + (lane >> 2);
    const int srow1 = srow0 + 16;
    const int cp    = lane & 3;
    const int gc0 = cp ^ ((srow0 >> 1) & 3);
    const int gc1 = cp ^ ((srow1 >> 1) & 3);

    const bf16_t* Ag0 = A  + (size_t)(bm + srow0) * K + gc0 * 8;
    const bf16_t* Ag1 = A  + (size_t)(bm + srow1) * K + gc1 * 8;
    const bf16_t* Bg0 = Bt + (size_t)(bn + srow0) * K + gc0 * 8;
    const bf16_t* Bg1 = Bt + (size_t)(bn + srow1) * K + gc1 * 8;

    floatx4 acc[4][4];
    #pragma unroll
    for (int i = 0; i < 4; ++i)
        #pragma unroll
        for (int j = 0; j < 4; ++j)
            #pragma unroll
            for (int r = 0; r < 4; ++r) acc[i][j][r] = 0.f;

    const int NIT = K / BK;
    auto stage = [&](int buf, int k0) {
        gll16(Ag0 + k0, &As[buf][wave * 32][0]);
        gll16(Ag1 + k0, &As[buf][wave * 32 + 16][0]);
        gll16(Bg0 + k0, &Bs[buf][wave * 32][0]);
        gll16(Bg1 + k0, &Bs[buf][wave * 32 + 16][0]);
    };
    stage(0, 0);
    stage(1, BK);

    for (int i = 0; i < NIT; ++i) {
        BAR();
        if (i + 2 < NIT) {
            stage((i + 2) % 3, (i + 2) * BK);
            WAIT(8);
        } else if (i + 1 < NIT) {
            WAIT(4);
        } else {
            WAIT(0);
        }
        BAR();

        const int buf = i % 3;
        bf16x8 af[4], bfr[4];
        #pragma unroll
        for (int ii = 0; ii < 4; ++ii) {
            const int row = wm + ii * 16 + lm;
            af[ii] = *(const bf16x8*)&As[buf][row][(lq ^ ((row >> 1) & 3)) * 8];
        }
        #pragma unroll
        for (int j = 0; j < 4; ++j) {
            const int row = wn + j * 16 + lm;
            bfr[j] = *(const bf16x8*)&Bs[buf][row][(lq ^ ((row >> 1) & 3)) * 8];
        }
        #pragma unroll
        for (int ii = 0; ii < 4; ++ii)
            #pragma unroll
            for (int j = 0; j < 4; ++j)
                acc[ii][j] = __builtin_amdgcn_mfma_f32_16x16x32_bf16(af[ii], bfr[j], acc[ii][j], 0, 0, 0);
    }

    if (blockIdx.z == 2) {
        #pragma unroll
        for (int i = 0; i < 4; ++i) {
            const int row0 = bm + wm + i * 16 + lq * 4;
            #pragma unroll
            for (int j = 0; j < 4; ++j) {
                const int col = bn + wn + j * 16 + lm;
                const float bb = bias[col];
                bf16x4 pk;
                #pragma unroll
                for (int r = 0; r < 4; ++r) pk[r] = (bf16_t)(acc[i][j][r] + bb);
                *(bf16x4*)(VtOut + (size_t)col * M + row0) = pk;
            }
        }
    } else {
        bf16_t* C = (blockIdx.z == 0) ? Qout : Kout;
        #pragma unroll
        for (int i = 0; i < 4; ++i) {
            const int row0 = bm + wm + i * 16 + lq * 4;
            #pragma unroll
            for (int j = 0; j < 4; ++j) {
                const int col = bn + wn + j * 16 + lm;
                const float bb = bias[col];
                #pragma unroll
                for (int r = 0; r < 4; ++r)
                    C[(size_t)(row0 + r) * N + col] = (bf16_t)(acc[i][j][r] + bb);
            }
        }
    }
}

// Split-K GEMM (O-projection): z in {0,1,2} covers a K-slice, writes f32 partials.
__global__ __launch_bounds__(256) void k_gemm_splitk(
    const bf16_t* __restrict__ A, const bf16_t* __restrict__ Bt,
    float* __restrict__ P0, float* __restrict__ P1, float* __restrict__ P2,
    int M, int N, int K)
{
    __shared__ bf16_t As[3][BM][BK];
    __shared__ bf16_t Bs[3][BN][BK];

    const int t    = threadIdx.x;
    const int lane = t & 63;
    const int wave = t >> 6;
    const int wm = (wave >> 1) * 64;
    const int wn = (wave & 1) * 64;
    const int bm = blockIdx.y * BM;
    const int bn = blockIdx.x * BN;
    const int lm = lane & 15;
    const int lq = lane >> 4;
    const int z  = blockIdx.z;

    const int nit_all = K / BK;
    const int it0 = (z * nit_all) / 3;
    const int it1 = ((z + 1) * nit_all) / 3;
    const int NIT = it1 - it0;
    const int kbase = it0 * BK;

    const int srow0 = wave * 32 + (lane >> 2);
    const int srow1 = srow0 + 16;
    const int cp    = lane & 3;
    const int gc0 = cp ^ ((srow0 >> 1) & 3);
    const int gc1 = cp ^ ((srow1 >> 1) & 3);

    const bf16_t* Ag0 = A  + (size_t)(bm + srow0) * K + kbase + gc0 * 8;
    const bf16_t* Ag1 = A  + (size_t)(bm + srow1) * K + kbase + gc1 * 8;
    const bf16_t* Bg0 = Bt + (size_t)(bn + srow0) * K + kbase + gc0 * 8;
    const bf16_t* Bg1 = Bt + (size_t)(bn + srow1) * K + kbase + gc1 * 8;

    floatx4 acc[4][4];
    #pragma unroll
    for (int i = 0; i < 4; ++i)
        #pragma unroll
        for (int j = 0; j < 4; ++j)
            #pragma unroll
            for (int r = 0; r < 4; ++r) acc[i][j][r] = 0.f;

    auto stage = [&](int buf, int k0) {
        gll16(Ag0 + k0, &As[buf][wave * 32][0]);
        gll16(Ag1 + k0, &As[buf][wave * 32 + 16][0]);
        gll16(Bg0 + k0, &Bs[buf][wave * 32][0]);
        gll16(Bg1 + k0, &Bs[buf][wave * 32 + 16][0]);
    };
    stage(0, 0);
    if (1 < NIT) stage(1, BK);

    for (int i = 0; i < NIT; ++i) {
        BAR();
        if (i + 2 < NIT) {
            stage((i + 2) % 3, (i + 2) * BK);
            WAIT(8);
        } else if (i + 1 < NIT) {
            WAIT(4);
        } else {
            WAIT(0);
        }
        BAR();

        const int buf = i % 3;
        bf16x8 af[4], bfr[4];
        #pragma unroll
        for (int ii = 0; ii < 4; ++ii) {
            const int row = wm + ii * 16 + lm;
            af[ii] = *(const bf16x8*)&As[buf][row][(lq ^ ((row >> 1) & 3)) * 8];
        }
        #pragma unroll
        for (int j = 0; j < 4; ++j) {
            const int row = wn + j * 16 + lm;
            bfr[j] = *(const bf16x8*)&Bs[buf][row][(lq ^ ((row >> 1) & 3)) * 8];
        }
        #pragma unroll
        for (int ii = 0; ii < 4; ++ii)
            #pragma unroll
            for (int j = 0; j < 4; ++j)
                acc[ii][j] = __builtin_amdgcn_mfma_f32_16x16x32_bf16(af[ii], bfr[j], acc[ii][j], 0, 0, 0);
    }

    float* C = (z == 0) ? P0 : (z == 1) ? P1 : P2;
    #pragma unroll
    for (int i = 0; i < 4; ++i) {
        const int row0 = bm + wm + i * 16 + lq * 4;
        #pragma unroll
        for (int j = 0; j < 4; ++j) {
            const int col = bn + wn + j * 16 + lm;
            #pragma unroll
            for (int r = 0; r < 4; ++r)
                C[(size_t)(row0 + r) * N + col] = acc[i][j][r];
        }
    }
}

// out = bias + p0 + p1 + p2
__global__ __launch_bounds__(256) void k_reduce_bias(
    const float* __restrict__ P0, const float* __restrict__ P1,
    const float* __restrict__ P2, const float* __restrict__ bias,
    float* __restrict__ out)
{
    const int i = (blockIdx.x * 256 + threadIdx.x) * 4;
    const float4 b  = *(const float4*)(bias + (i & (D_DIM - 1)));
    const float4 a0 = *(const float4*)(P0 + i);
    const float4 a1 = *(const float4*)(P1 + i);
    const float4 a2 = *(const float4*)(P2 + i);
    float4 o;
    o.x = b.x + a0.x + a1.x + a2.x;
    o.y = b.y + a0.y + a1.y + a2.y;
    o.z = b.z + a0.z + a1.z + a2.z;
    o.w = b.w + a0.w + a1.w + a2.w;
    *(float4*)(out + i) = o;
}

// ---------------- RMSNorm (full D) + interleaved RoPE, bf16 in-place ----------------
__global__ __launch_bounds__(256) void k_norm_rope(
    bf16_t* __restrict__ Q, bf16_t* __restrict__ Kb_,
    const float* __restrict__ qw, const float* __restrict__ kw,
    const float* __restrict__ cosb, const float* __restrict__ sinb)
{
    bf16_t* X = (blockIdx.z == 0) ? Q : Kb_;
    const float* w = (blockIdx.z == 0) ? qw : kw;
    const int row = blockIdx.x;
    const int t = threadIdx.x;
    const size_t base = (size_t)row * D_DIM + t * 8;

    const bf16x8 xv = *(const bf16x8*)(X + base);
    float x[8];
    #pragma unroll
    for (int i = 0; i < 8; ++i) x[i] = (float)xv[i];

    float ss = 0.f;
    #pragma unroll
    for (int i = 0; i < 8; ++i) ss += x[i] * x[i];
    #pragma unroll
    for (int off = 32; off; off >>= 1) ss += __shfl_xor(ss, off);
    __shared__ float red[4];
    if ((t & 63) == 0) red[t >> 6] = ss;
    __syncthreads();
    const float tot = red[0] + red[1] + red[2] + red[3];
    const float rms = rsqrtf(tot * (1.0f / D_DIM) + 1e-6f);

    float wv[8], c[8], sn[8];
    { float4 a = *(const float4*)(w + t * 8); float4 b = *(const float4*)(w + t * 8 + 4);
      wv[0]=a.x; wv[1]=a.y; wv[2]=a.z; wv[3]=a.w; wv[4]=b.x; wv[5]=b.y; wv[6]=b.z; wv[7]=b.w; }
    const size_t cbase = (size_t)row * D_DIM + ((t * 8) & 63);
    { float4 a = *(const float4*)(cosb + cbase); float4 b = *(const float4*)(cosb + cbase + 4);
      c[0]=a.x; c[1]=a.y; c[2]=a.z; c[3]=a.w; c[4]=b.x; c[5]=b.y; c[6]=b.z; c[7]=b.w; }
    { float4 a = *(const float4*)(sinb + cbase); float4 b = *(const float4*)(sinb + cbase + 4);
      sn[0]=a.x; sn[1]=a.y; sn[2]=a.z; sn[3]=a.w; sn[4]=b.x; sn[5]=b.y; sn[6]=b.z; sn[7]=b.w; }

    bf16x8 o;
    #pragma unroll
    for (int p = 0; p < 4; ++p) {
        const float e  = x[2*p]     * rms * wv[2*p];
        const float od = x[2*p + 1] * rms * wv[2*p + 1];
        o[2*p]     = (bf16_t)(e * c[2*p]     - od * sn[2*p]);
        o[2*p + 1] = (bf16_t)(od * c[2*p + 1] + e * sn[2*p + 1]);
    }
    *(bf16x8*)(X + base) = o;
}

// ---------------- MFMA flash attention, software-pipelined chunks ----------------
// Per iter: [stage(c+1) | QK(c) -> stNew | exp(c-1) from stOld | PV(c-1)]
#define LDPQ 72

__global__ __launch_bounds__(256) void k_flash(
    const bf16_t* __restrict__ Qb, const bf16_t* __restrict__ Kb,
    const bf16_t* __restrict__ Vt, bf16_t* __restrict__ Ob)
{
    // XCD-aware mapping: each XCD (bid&7) handles 4 heads -> 2 MB KV fits its L2
    const int bid = blockIdx.x;
    const int jj  = bid >> 3;
    const int h   = ((bid & 7) << 2) | (jj >> 4);
    const int qblk = jj & 15;
    const int hc = h * DH;
    const int t = threadIdx.x;
    const int wave = t >> 6, lane = t & 63;
    const int ln = lane & 31, hf = lane >> 5;
    const int qw = qblk * 128 + wave * 32;

    __shared__ bf16_t Ks[3][64][64];     // [key][dh], swizzled
    __shared__ bf16_t Vs[3][64][64];     // [d][key],  swizzled
    __shared__ bf16_t Ps[4][32][LDPQ];   // per-wave [q][key] (single buf: in-order DS)
    __shared__ float  Lw[4][32];

    bf16x8 bq[4];
    #pragma unroll
    for (int kt = 0; kt < 4; ++kt)
        bq[kt] = *(const bf16x8*)(Qb + (size_t)(qw + ln) * D_DIM + hc + kt * 16 + hf * 8);

    const int r0  = wave * 16 + (lane >> 3);
    const int r1  = r0 + 8;
    const int cp8 = lane & 7;
    const int gcA = cp8 ^ (r0 & 7);
    const int gcB = cp8 ^ (r1 & 7);
    const bf16_t* kg0 = Kb + (size_t)r0 * D_DIM + hc + gcA * 8;
    const bf16_t* kg1 = Kb + (size_t)r1 * D_DIM + hc + gcB * 8;
    const bf16_t* vg0 = Vt + (size_t)(hc + r0) * S_LEN + gcA * 8;
    const bf16_t* vg1 = Vt + (size_t)(hc + r1) * S_LEN + gcB * 8;

    auto stageKV = [&](int buf, int kc) {
        gll16(kg0 + (size_t)kc * D_DIM, &Ks[buf][wave * 16][0]);
        gll16(kg1 + (size_t)kc * D_DIM, &Ks[buf][wave * 16 + 8][0]);
        gll16(vg0 + kc, &Vs[buf][wave * 16][0]);
        gll16(vg1 + kc, &Vs[buf][wave * 16 + 8][0]);
    };

    floatx16 o0, o1;
    #pragma unroll
    for (int r = 0; r < 16; ++r) { o0[r] = 0.f; o1[r] = 0.f; }
    float lsum = 0.f;

    const int swz = ln & 7;
    const float c_exp = 0.125f * 1.44269504089f;
    const int NCH = S_LEN / 64;   // 32 chunks

    auto qk = [&](int buf, floatx16& s0, floatx16& s1) {
        #pragma unroll
        for (int r = 0; r < 16; ++r) { s0[r] = 0.f; s1[r] = 0.f; }
        #pragma unroll
        for (int kt = 0; kt < 4; ++kt) {
            const int ch = 2 * kt + hf;
            const bf16x8 a0 = *(const bf16x8*)&Ks[buf][ln]     [(ch ^ swz) * 8];
            const bf16x8 a1 = *(const bf16x8*)&Ks[buf][32 + ln][(ch ^ swz) * 8];
            s0 = __builtin_amdgcn_mfma_f32_32x32x16_bf16(a0, bq[kt], s0, 0, 0, 0);
            s1 = __builtin_amdgcn_mfma_f32_32x32x16_bf16(a1, bq[kt], s1, 0, 0, 0);
        }
    };
    auto expv = [&](const floatx16& s0, const floatx16& s1) {
        #pragma unroll
        for (int g = 0; g < 4; ++g) {
            bf16x4 p0, p1;
            #pragma unroll
            for (int r4 = 0; r4 < 4; ++r4) {
                const float e0 = __builtin_amdgcn_exp2f(s0[4 * g + r4] * c_exp);
                const float e1 = __builtin_amdgcn_exp2f(s1[4 * g + r4] * c_exp);
                p0[r4] = (bf16_t)e0; p1[r4] = (bf16_t)e1;
                lsum += e0 + e1;
            }
            *(bf16x4*)&Ps[wave][ln][8 * g + 4 * hf]      = p0;
            *(bf16x4*)&Ps[wave][ln][32 + 8 * g + 4 * hf] = p1;
        }
    };
    auto pv = [&](int buf) {
        #pragma unroll
        for (int kt = 0; kt < 4; ++kt) {
            const int ch = 2 * kt + hf;
            const bf16x8 ap  = *(const bf16x8*)&Ps[wave][ln][kt * 16 + hf * 8];
            const bf16x8 bv0 = *(const bf16x8*)&Vs[buf][ln]     [(ch ^ swz) * 8];
            const bf16x8 bv1 = *(const bf16x8*)&Vs[buf][32 + ln][(ch ^ swz) * 8];
            o0 = __builtin_amdgcn_mfma_f32_32x32x16_bf16(ap, bv0, o0, 0, 0, 0);
            o1 = __builtin_amdgcn_mfma_f32_32x32x16_bf16(ap, bv1, o1, 0, 0, 0);
        }
    };

    stageKV(0, 0);
    stageKV(1, 64);

    floatx16 stA0, stA1, stB0, stB1;

    auto pipe_step = [&](int c, floatx16& n0_, floatx16& n1_,
                         floatx16& p0_, floatx16& p1_) {
        BAR();                                   // prior readers of overwritten buf done
        if (c >= 1 && c + 1 < NCH) {
            stageKV((c + 1) % 3, (c + 1) * 64);
            WAIT(4);                             // set c landed (own-wave vmcnt)
        } else if (c == 0) {
            WAIT(4);                             // S0 done (S0,S1 outstanding)
        } else {
            WAIT(0);                             // tail
        }
        BAR();                                   // all waves' set-c visible
        qk(c % 3, n0_, n1_);                     // -> st(c)
        if (c > 0) {
            expv(p0_, p1_);                      // exp of st(c-1), overlaps qk MFMAs
            DSWAIT();
            pv((c - 1) % 3);                     // O += P(c-1) V(c-1)
        }
    };

    for (int c2 = 0; c2 < NCH; c2 += 2) {
        pipe_step(c2,     stA0, stA1, stB0, stB1);
        pipe_step(c2 + 1, stB0, stB1, stA0, stA1);
    }
    // drain: chunk NCH-1 (st in stB since NCH even)
    expv(stB0, stB1);
    DSWAIT();
    pv((NCH - 1) % 3);

    // l[q=ln] = own half + partner half; redistribute to C-layout rows via LDS
    const float ltot = lsum + __shfl_xor(lsum, 32);
    if (hf == 0) Lw[wave][ln] = ltot;
    DSWAIT();
    float4 li[4];
    li[0] = *(const float4*)&Lw[wave][4 * hf];
    li[1] = *(const float4*)&Lw[wave][8 + 4 * hf];
    li[2] = *(const float4*)&Lw[wave][16 + 4 * hf];
    li[3] = *(const float4*)&Lw[wave][24 + 4 * hf];

    #pragma unroll
    for (int r = 0; r < 16; ++r) {
        const int row = (r & 3) + 8 * (r >> 2) + 4 * hf;
        const float lv = (r & 3) == 0 ? li[r >> 2].x : (r & 3) == 1 ? li[r >> 2].y
                       : (r & 3) == 2 ? li[r >> 2].z : li[r >> 2].w;
        const float inv = 1.0f / lv;
        Ob[(size_t)(qw + row) * D_DIM + hc + ln]      = (bf16_t)(o0[r] * inv);
        Ob[(size_t)(qw + row) * D_DIM + hc + 32 + ln] = (bf16_t)(o1[r] * inv);
    }
}

// ---------------- launcher ----------------
extern "C" void kernel_launch(void* const* d_in, const int* in_sizes, int n_in,
                              void* d_out, int out_size, void* d_ws, size_t ws_size,
                              hipStream_t stream) {
    const float* hs   = (const float*)d_in[0];
    const float* cosb = (const float*)d_in[1];
    const float* sinb = (const float*)d_in[2];
    const float* Wq   = (const float*)d_in[3];
    const float* bq   = (const float*)d_in[4];
    const float* Wk   = (const float*)d_in[5];
    const float* bk   = (const float*)d_in[6];
    const float* Wv   = (const float*)d_in[7];
    const float* bv   = (const float*)d_in[8];
    const float* qw   = (const float*)d_in[9];
    const float* kw   = (const float*)d_in[10];
    const float* Wo   = (const float*)d_in[11];
    const float* bo   = (const float*)d_in[12];
    float* out = (float*)d_out;

    char* ws = (char*)d_ws;
    bf16_t* Xb  = (bf16_t*)(ws);
    bf16_t* Wqt = (bf16_t*)(ws + ((size_t)8  << 20));
    bf16_t* Wkt = (bf16_t*)(ws + ((size_t)16 << 20));
    bf16_t* Wvt = (bf16_t*)(ws + ((size_t)24 << 20));
    bf16_t* Wot = (bf16_t*)(ws + ((size_t)32 << 20));
    bf16_t* Qb  = (bf16_t*)(ws + ((size_t)40 << 20));
    bf16_t* Kb  = (bf16_t*)(ws + ((size_t)48 << 20));
    bf16_t* Vt  = (bf16_t*)(ws + ((size_t)56 << 20));
    bf16_t* Ob  = (bf16_t*)(ws + ((size_t)64 << 20));
    float*  P0  = (float*) (ws);                       // aliases Xb/Wqt (dead)
    float*  P1  = (float*) (ws + ((size_t)16 << 20));  // aliases Wkt/Wvt (dead)
    float*  P2  = (float*) (ws + ((size_t)48 << 20));  // aliases Kb/Vt (dead)

    const int n = S_LEN * D_DIM;

    // fused cvt + 4x weight transpose
    k_prep<<<dim3(32, 32, 5), 256, 0, stream>>>(hs, Xb, Wq, Wk, Wv, Wo, Wqt, Wkt, Wvt, Wot);

    // QKV projection: Q,K bf16 row-major; V -> bf16 per-head transposed Vt
    k_gemm_qkv<<<dim3(D_DIM / BN, S_LEN / BM, 3), 256, 0, stream>>>(
        Xb, Wqt, Wkt, Wvt, bq, bk, bv, Qb, Kb, Vt, S_LEN, D_DIM, D_DIM);

    // RMSNorm + RoPE, bf16 in-place
    k_norm_rope<<<dim3(S_LEN, 1, 2), 256, 0, stream>>>(Qb, Kb, qw, kw, cosb, sinb);

    // MFMA flash attention -> bf16 activations
    k_flash<<<512, 256, 0, stream>>>(Qb, Kb, Vt, Ob);

    // output projection: split-K=3 partials + reduce(+bias)
    k_gemm_splitk<<<dim3(D_DIM / BN, S_LEN / BM, 3), 256, 0, stream>>>(
        Ob, Wot, P0, P1, P2, S_LEN, D_DIM, D_DIM);
    k_reduce_bias<<<n / (256 * 4), 256, 0, stream>>>(P0, P1, P2, bo, out);
}